// Round 5
// baseline (407.337 us; speedup 1.0000x reference)
//
#include <hip/hip_runtime.h>
#include <stdint.h>

#define EMB 2048
#define NH 16
#define QRANK 1536
#define KVRANK 512
#define ROPED 64
#define NOPED 64
#define VD 128
#define QKD 128
#define SEQ 2048
#define BATCH 2
#define BS 4096            // BATCH*SEQ
#define BHD 32             // BATCH*NH
#define NCOMB 2112         // QRANK + KVRANK + ROPED
#define LOG2E 1.4426950408889634f
#define NT (SEQ / 64)      // 32 KV tiles

typedef __attribute__((ext_vector_type(4))) float f32x4;
typedef __attribute__((ext_vector_type(8))) short s16x8;
typedef __attribute__((ext_vector_type(4))) short s16x4;
typedef __attribute__((ext_vector_type(2))) unsigned int u32x2;

__device__ __forceinline__ float bf2f(unsigned short u) {
  return __uint_as_float(((unsigned int)u) << 16);
}
__device__ __forceinline__ unsigned short f2bf(float f) {
  unsigned int u = __float_as_uint(f);
  u += 0x7fff + ((u >> 16) & 1);
  return (unsigned short)(u >> 16);
}

__device__ __forceinline__ float vexp2(float x) {
#if __has_builtin(__builtin_amdgcn_exp2f)
  return __builtin_amdgcn_exp2f(x);
#else
  return exp2f(x);
#endif
}

// pack hi16(e1):hi16(e0) into one dword (bf16 truncation)
__device__ __forceinline__ unsigned int pk_bf16_trunc(float e0, float e1) {
#if __has_builtin(__builtin_amdgcn_perm)
  return __builtin_amdgcn_perm(__float_as_uint(e1), __float_as_uint(e0), 0x07060302u);
#else
  return (__float_as_uint(e1) & 0xffff0000u) | (__float_as_uint(e0) >> 16);
#endif
}

// CDNA4 lane-row swaps (both outputs used).
__device__ __forceinline__ void pl32swap(unsigned int& a, unsigned int& b) {
#if __has_builtin(__builtin_amdgcn_permlane32_swap)
  u32x2 r = __builtin_amdgcn_permlane32_swap(a, b, false, false);
  a = r.x; b = r.y;
#else
  asm("v_permlane32_swap_b32 %0, %1" : "+v"(a), "+v"(b));
#endif
}
__device__ __forceinline__ void pl16swap(unsigned int& a, unsigned int& b) {
#if __has_builtin(__builtin_amdgcn_permlane16_swap)
  u32x2 r = __builtin_amdgcn_permlane16_swap(a, b, false, false);
  a = r.x; b = r.y;
#else
  asm("v_permlane16_swap_b32 %0, %1" : "+v"(a), "+v"(b));
#endif
}

__device__ __forceinline__ void gld_lds16(const unsigned short* g, unsigned short* l) {
  __builtin_amdgcn_global_load_lds((const __attribute__((address_space(1))) void*)g,
                                   (__attribute__((address_space(3))) void*)l,
                                   16, 0, 0);
}

// ---------------- fused cast f32 -> bf16, all 6 tensors, one launch ----------
#define N4_X   (BS * EMB / 4)
#define N4_QA  (QRANK * EMB / 4)
#define N4_KVA ((KVRANK + ROPED) * EMB / 4)
#define N4_QB  (NH * QKD * QRANK / 4)
#define N4_KVB (NH * 192 * KVRANK / 4)
#define N4_O   (EMB * NH * VD / 4)
#define N4_TOT (N4_X + N4_QA + N4_KVA + N4_QB + N4_KVB + N4_O)

__global__ void cast_all(const float* __restrict__ x, const float* __restrict__ qa,
                         const float* __restrict__ kva, const float* __restrict__ qb,
                         const float* __restrict__ kvb, const float* __restrict__ ow,
                         unsigned short* __restrict__ Xb, unsigned short* __restrict__ Wcomb,
                         unsigned short* __restrict__ Wqb, unsigned short* __restrict__ Wkvb,
                         unsigned short* __restrict__ Wo) {
  int i = blockIdx.x * blockDim.x + threadIdx.x;
  int stride = gridDim.x * blockDim.x;
  for (; i < N4_TOT; i += stride) {
    const float4* src;
    ushort4* dst;
    int j = i;
    if (j < N4_X) { src = (const float4*)x; dst = (ushort4*)Xb; }
    else if ((j -= N4_X) < N4_QA) { src = (const float4*)qa; dst = (ushort4*)Wcomb; }
    else if ((j -= N4_QA) < N4_KVA) { src = (const float4*)kva; dst = (ushort4*)(Wcomb + (size_t)QRANK * EMB); }
    else if ((j -= N4_KVA) < N4_QB) { src = (const float4*)qb; dst = (ushort4*)Wqb; }
    else if ((j -= N4_QB) < N4_KVB) { src = (const float4*)kvb; dst = (ushort4*)Wkvb; }
    else { j -= N4_KVB; src = (const float4*)ow; dst = (ushort4*)Wo; }
    float4 v = src[j];
    ushort4 o;
    o.x = f2bf(v.x); o.y = f2bf(v.y); o.z = f2bf(v.z); o.w = f2bf(v.w);
    dst[j] = o;
  }
}

// ---------------- GEMM: C[M,N] = A[M,K(lda)] * W[N,K(ldw)]^T ----------------
template <int OUT_F32>
__global__ __launch_bounds__(256, 2) void gemm_bt(
    const unsigned short* __restrict__ A, int lda,
    const unsigned short* __restrict__ W, int ldw,
    void* __restrict__ C, int M, int N, int K)
{
  __shared__ __align__(16) unsigned short As[128 * 64];
  __shared__ __align__(16) unsigned short Ws[128 * 64];
  const int tid = threadIdx.x;
  const int wave = tid >> 6;
  const int lane = tid & 63;
  const int ln = lane & 15;
  const int quad = lane >> 4;
  const int bm = blockIdx.y * 128;
  const int bn = blockIdx.x * 128;
  const int wm = (wave >> 1) * 64;
  const int wn = (wave & 1) * 64;

  f32x4 acc[4][4] = {};

  const int rel8 = lane >> 3;
  const int csw = ((lane & 7) ^ rel8) * 8;

  for (int k0 = 0; k0 < K; k0 += 64) {
#pragma unroll
    for (int it = 0; it < 4; ++it) {
      int rb = wave * 32 + it * 8;
      gld_lds16(A + (size_t)(bm + rb + rel8) * lda + k0 + csw, &As[rb * 64]);
    }
#pragma unroll
    for (int it = 0; it < 4; ++it) {
      int rb = wave * 32 + it * 8;
      int wr = bn + rb + rel8;
      if (wr >= N) wr = N - 1;
      gld_lds16(W + (size_t)wr * ldw + k0 + csw, &Ws[rb * 64]);
    }
    __syncthreads();
#pragma unroll
    for (int kk = 0; kk < 64; kk += 32) {
      s16x8 a[4], b[4];
#pragma unroll
      for (int mt = 0; mt < 4; ++mt)
        a[mt] = *(const s16x8*)&As[(wm + mt * 16 + ln) * 64 + ((kk / 8 + quad) ^ (ln & 7)) * 8];
#pragma unroll
      for (int nt = 0; nt < 4; ++nt)
        b[nt] = *(const s16x8*)&Ws[(wn + nt * 16 + ln) * 64 + ((kk / 8 + quad) ^ (ln & 7)) * 8];
#pragma unroll
      for (int mt = 0; mt < 4; ++mt)
#pragma unroll
        for (int nt = 0; nt < 4; ++nt)
          acc[mt][nt] = __builtin_amdgcn_mfma_f32_16x16x32_bf16(a[mt], b[nt], acc[mt][nt], 0, 0, 0);
    }
    __syncthreads();
  }
#pragma unroll
  for (int mt = 0; mt < 4; ++mt) {
    int row = bm + wm + mt * 16 + quad * 4;
#pragma unroll
    for (int nt = 0; nt < 4; ++nt) {
      int col = bn + wn + nt * 16 + ln;
      if (col < N) {
#pragma unroll
        for (int r = 0; r < 4; ++r) {
          float v = acc[mt][nt][r];
          if (OUT_F32)
            ((float*)C)[(size_t)(row + r) * N + col] = v;
          else
            ((unsigned short*)C)[(size_t)(row + r) * N + col] = f2bf(v);
        }
      }
    }
  }
}

// ---------------- q GEMM: fused RoPE + log2e pre-scale + (B,H,S,128) store ---
__global__ __launch_bounds__(256, 2) void gemm_q_rope(
    const unsigned short* __restrict__ A, int lda,
    const unsigned short* __restrict__ W, int ldw,
    unsigned short* __restrict__ Qry, int K)
{
  __shared__ __align__(16) unsigned short As[128 * 64];
  __shared__ __align__(16) unsigned short Ws[128 * 64];
  const int tid = threadIdx.x;
  const int wave = tid >> 6;
  const int lane = tid & 63;
  const int ln = lane & 15;
  const int quad = lane >> 4;
  const int bm = blockIdx.y * 128;
  const int bn = blockIdx.x * 128;
  const int wm = (wave >> 1) * 64;
  const int wn = (wave & 1) * 64;

  f32x4 acc[4][4] = {};
  const int rel8 = lane >> 3;
  const int csw = ((lane & 7) ^ rel8) * 8;

  for (int k0 = 0; k0 < K; k0 += 64) {
#pragma unroll
    for (int it = 0; it < 4; ++it) {
      int rb = wave * 32 + it * 8;
      gld_lds16(A + (size_t)(bm + rb + rel8) * lda + k0 + csw, &As[rb * 64]);
    }
#pragma unroll
    for (int it = 0; it < 4; ++it) {
      int rb = wave * 32 + it * 8;
      gld_lds16(W + (size_t)(bn + rb + rel8) * ldw + k0 + csw, &Ws[rb * 64]);
    }
    __syncthreads();
#pragma unroll
    for (int kk = 0; kk < 64; kk += 32) {
      s16x8 a[4], b[4];
#pragma unroll
      for (int mt = 0; mt < 4; ++mt)
        a[mt] = *(const s16x8*)&As[(wm + mt * 16 + ln) * 64 + ((kk / 8 + quad) ^ (ln & 7)) * 8];
#pragma unroll
      for (int nt = 0; nt < 4; ++nt)
        b[nt] = *(const s16x8*)&Ws[(wn + nt * 16 + ln) * 64 + ((kk / 8 + quad) ^ (ln & 7)) * 8];
#pragma unroll
      for (int mt = 0; mt < 4; ++mt)
#pragma unroll
        for (int nt = 0; nt < 4; ++nt)
          acc[mt][nt] = __builtin_amdgcn_mfma_f32_16x16x32_bf16(a[mt], b[nt], acc[mt][nt], 0, 0, 0);
    }
    __syncthreads();
  }
  const bool odd = (ln & 1);
#pragma unroll
  for (int mt = 0; mt < 4; ++mt) {
    int rowb = bm + wm + mt * 16 + quad * 4;
#pragma unroll
    for (int nt = 0; nt < 4; ++nt) {
      int col = bn + wn + nt * 16 + ln;
      int h = col >> 7, d = col & 127;
#pragma unroll
      for (int r = 0; r < 4; ++r) {
        float v = acc[mt][nt][r];
        float other = __shfl_xor(v, 1);
        int row = rowb + r;
        int b = row >> 11, s = row & 2047;
        float y = v;
        if (d >= NOPED) {
          int i = (d - NOPED) >> 1;
          float theta = exp2f(-(float)i * (13.287712379549449f / 32.f));
          float ang = (float)s * theta;
          float sn, c;
          sincosf(ang, &sn, &c);
          y = v * c + (odd ? other * sn : -other * sn);
        }
        y *= LOG2E;   // fold softmax exp->exp2 conversion into Q
        Qry[((size_t)(b * NH + h) * SEQ + s) * QKD + d] = f2bf(y);
      }
    }
  }
}

// ---------------- fused prep: Key (nope + RoPE) AND V^T, one KVB pass --------
// Replaces prep_key (4096 blocks) + transpose_v (1024 blocks): one kernel,
// 1024 blocks, single read of the KVB tile. krot is recomputed per head
// (16x redundant trig ~= 2 us total) to keep the transpose-friendly
// (bh, s-tile) grid.
__global__ void prep_kv(const unsigned short* __restrict__ kvb,
                        const unsigned short* __restrict__ cqkv,
                        unsigned short* __restrict__ Key,
                        unsigned short* __restrict__ VT) {
  __shared__ unsigned short vt[64][132];
  __shared__ unsigned short kr[64][64];
  int blk = blockIdx.x;
  int bh = blk >> 5, st = blk & 31;
  int b = bh >> 4, h = bh & 15;
  int s0 = st * 64;
  int tid = threadIdx.x;

  // krot: 64 rows x 32 pairs
  for (int idx = tid; idx < 64 * 32; idx += 256) {
    int sl = idx >> 5, i = idx & 31;
    int s = s0 + sl;
    const unsigned short* rp = cqkv + (size_t)(b * SEQ + s) * NCOMB + QRANK + KVRANK;
    float x0 = bf2f(rp[2 * i]);
    float x1 = bf2f(rp[2 * i + 1]);
    float theta = exp2f(-(float)i * (13.287712379549449f / 32.f));
    float ang = (float)s * theta;
    float sn, c;
    sincosf(ang, &sn, &c);
    kr[sl][2 * i] = f2bf(x0 * c - x1 * sn);
    kr[sl][2 * i + 1] = f2bf(x1 * c + x0 * sn);
  }
  // V tile load (16B vectors; kvb offset h*192+64 elems = 384h+128 B, 16B-aligned)
  for (int idx = tid; idx < 64 * 16; idx += 256) {
    int sl = idx >> 4, dc = idx & 15;
    s16x8 v = *(const s16x8*)(kvb + (size_t)(b * SEQ + s0 + sl) * (NH * 192) + h * 192 + NOPED + dc * 8);
    *(s16x8*)&vt[sl][dc * 8] = v;
  }
  __syncthreads();
  // Key write: d<64 nope straight from kvb, d>=64 from kr
  for (int idx = tid; idx < 64 * 128; idx += 256) {
    int sl = idx >> 7, d = idx & 127;
    unsigned short v;
    if (d < NOPED)
      v = kvb[(size_t)(b * SEQ + s0 + sl) * (NH * 192) + h * 192 + d];
    else
      v = kr[sl][d - NOPED];
    Key[((size_t)bh * SEQ + s0 + sl) * QKD + d] = v;
  }
  // V^T write
  for (int idx = tid; idx < 64 * 128; idx += 256) {
    int d = idx >> 6, sl = idx & 63;
    VT[((size_t)bh * VD + d) * SEQ + s0 + sl] = vt[sl][d];
  }
}

// ---------------- flash attention v11: 3 blocks/CU via 48KB LDS --------------
// v10 post-mortem: intra-wave QK(kt)||SM+PV(kt-1) interleave was NEUTRAL
// (88->86.6us, MfmaUtil stuck 32%). Revised theory: at 2 blocks/CU every
// wave on a SIMD is a barrier-locked companion at the SAME phase -> MFMA and
// VALU demand alternate in lockstep, pipes never overlap (m114 needs waves at
// INDEPENDENT phases = different blocks). Fix: LDS 80->48KB (K tile single-
// buffered 16KB + V dbuf 32KB) -> 3 blocks/CU, 3 waves/SIMD from 3
// independently-drifting blocks. K(kt) is fully consumed by QK early in the
// tile; mid-barrier, then stage K(kt+1) in place (softmax+PV ~1500cy covers
// the load). V(kt+1) prefetched at loop top (full-tile cover). Per-wave
// vmcnt(0) BEFORE the end barrier makes all waves' staging visible after it.
// All LDS layouts identical to v9 (measured 0 bank conflicts).
__global__ __launch_bounds__(256, 3) void flash_attn(
    const unsigned short* __restrict__ Q,
    const unsigned short* __restrict__ Kt,     // (BHD, SEQ, 128)
    const unsigned short* __restrict__ VT,     // (BHD, 128, SEQ)
    unsigned short* __restrict__ O)
{
  __shared__ __align__(16) unsigned short Ks[64 * 128];      // 16 KB, single
  __shared__ __align__(16) unsigned short Vs[2][128 * 64];   // 32 KB, dbuf

  const int tid = threadIdx.x;
  const int wave = tid >> 6;
  const int lane = tid & 63;
  const int ln = lane & 15;
  const int quad = lane >> 4;
  const int bh = blockIdx.x;
  const int q0 = blockIdx.y * 128;
  const int b = bh >> 4, h = bh & 15;

  // ---- Q fragments straight from global (B-operand of S^T = K·Q^T)
  s16x8 qa[2][4];
#pragma unroll
  for (int mt = 0; mt < 2; ++mt) {
    const unsigned short* qrow = Q + ((size_t)bh * SEQ + q0 + wave * 32 + mt * 16 + ln) * QKD;
#pragma unroll
    for (int kx = 0; kx < 4; ++kx)
      qa[mt][kx] = *(const s16x8*)(qrow + kx * 32 + quad * 8);
  }

  const int krel = lane >> 4, kcch = lane & 15;
  const int vrel8 = lane >> 3;
  const int vc8 = (lane & 7) ^ vrel8;

  auto stage_k = [&](int kt) {
#pragma unroll
    for (int it = 0; it < 4; ++it) {
      int rb = wave * 16 + it * 4;
      int rr = rb + krel;
      int c = kcch ^ (rr & 15);
      gld_lds16(Kt + ((size_t)bh * SEQ + kt * 64 + rr) * QKD + c * 8, &Ks[rb * 128]);
    }
  };
  auto stage_v = [&](int buf, int kt) {
#pragma unroll
    for (int it = 0; it < 4; ++it) {
      int rb = wave * 32 + it * 8;
      gld_lds16(VT + ((size_t)bh * VD + rb + vrel8) * SEQ + kt * 64 + vc8 * 8, &Vs[buf][rb * 64]);
    }
  };

  f32x4 o[2][8] = {};              // o[mt][dt]: d = dt*16+quad*4+r, q = mt*16+ln
  float l_i[2] = {0.f, 0.f};

  // prologue: tile 0 fully staged
  stage_k(0);
  stage_v(0, 0);
  asm volatile("s_waitcnt vmcnt(0)" ::: "memory");
  asm volatile("s_barrier" ::: "memory");

  for (int kt = 0; kt < NT; ++kt) {
    // early V prefetch: Vs[(kt+1)&1] last read by PV(kt-1), done before the
    // previous end barrier -> safe to overwrite now.
    if (kt + 1 < NT)
      stage_v((kt + 1) & 1, kt + 1);

    // ---- S^T = K·Q^T from single-buffered Ks, acc pre-biased to -20
    f32x4 sc[2][4];
#pragma unroll
    for (int mt = 0; mt < 2; ++mt)
#pragma unroll
      for (int t = 0; t < 4; ++t)
        sc[mt][t] = (f32x4){-20.f, -20.f, -20.f, -20.f};
    __builtin_amdgcn_s_setprio(1);
#pragma unroll
    for (int kx = 0; kx < 4; ++kx) {
      s16x8 ak[4];
#pragma unroll
      for (int t = 0; t < 4; ++t)
        ak[t] = *(const s16x8*)&Ks[(t * 16 + ln) * 128 + ((kx * 4 + quad) ^ ln) * 8];
#pragma unroll
      for (int mt = 0; mt < 2; ++mt)
#pragma unroll
        for (int t = 0; t < 4; ++t)
          sc[mt][t] = __builtin_amdgcn_mfma_f32_16x16x32_bf16(ak[t], qa[mt][kx], sc[mt][t], 0, 0, 0);
    }
    __builtin_amdgcn_s_setprio(0);

    asm volatile("s_barrier" ::: "memory");   // all waves done reading Ks
    if (kt + 1 < NT)
      stage_k(kt + 1);                        // overwrite Ks in place

    // ---- softmax: p = exp2(sc), truncate-pack, permlane relayout to K=32 frag
    s16x8 pfrag[2][2];
#pragma unroll
    for (int mt = 0; mt < 2; ++mt) {
      float rs = 0.f;
      unsigned int pw[4][2];
#pragma unroll
      for (int t = 0; t < 4; ++t) {
        float e0 = vexp2(sc[mt][t][0]);
        float e1 = vexp2(sc[mt][t][1]);
        float e2 = vexp2(sc[mt][t][2]);
        float e3 = vexp2(sc[mt][t][3]);
        unsigned int p01 = pk_bf16_trunc(e0, e1);
        unsigned int p23 = pk_bf16_trunc(e2, e3);
        pw[t][0] = p01; pw[t][1] = p23;
        rs += (__uint_as_float(p01 << 16) + __uint_as_float(p01 & 0xffff0000u))
            + (__uint_as_float(p23 << 16) + __uint_as_float(p23 & 0xffff0000u));
      }
      rs += __shfl_xor(rs, 16);
      rs += __shfl_xor(rs, 32);
      l_i[mt] += rs;
#pragma unroll
      for (int W = 0; W < 2; ++W) {
        unsigned int u0 = pw[2 * W][0], v0 = pw[2 * W + 1][0];
        unsigned int u1 = pw[2 * W][1], v1 = pw[2 * W + 1][1];
        pl32swap(u0, v0); pl16swap(u0, v0);
        pl32swap(u1, v1); pl16swap(u1, v1);
        union { unsigned int u[4]; s16x8 v; } fb;
        fb.u[0] = u0;    // k_local = quad*8 + {0,1}
        fb.u[1] = u1;    // k_local = quad*8 + {2,3}
        fb.u[2] = v0;    // k_local = quad*8 + {4,5}
        fb.u[3] = v1;    // k_local = quad*8 + {6,7}
        pfrag[mt][W] = fb.v;
      }
    }

    // ---- O^T += V^T · P^T  (A = V b128 granules, conflict-free XOR pattern)
    const unsigned short* Vc = Vs[kt & 1];
    __builtin_amdgcn_s_setprio(1);
#pragma unroll
    for (int dt = 0; dt < 8; ++dt) {
      s16x8 av0 = *(const s16x8*)&Vc[(dt * 16 + ln) * 64 + ((quad ^ (ln & 7)) * 8)];
      s16x8 av1 = *(const s16x8*)&Vc[(dt * 16 + ln) * 64 + (((4 + quad) ^ (ln & 7)) * 8)];
#pragma unroll
      for (int mt = 0; mt < 2; ++mt) {
        o[mt][dt] = __builtin_amdgcn_mfma_f32_16x16x32_bf16(av0, pfrag[mt][0], o[mt][dt], 0, 0, 0);
        o[mt][dt] = __builtin_amdgcn_mfma_f32_16x16x32_bf16(av1, pfrag[mt][1], o[mt][dt], 0, 0, 0);
      }
    }
    __builtin_amdgcn_s_setprio(0);

    // per-wave drain of its own K(kt+1)/V(kt+1) loads, THEN barrier: after it,
    // every wave's staging is complete -> next QK/PV may read.
    asm volatile("s_waitcnt vmcnt(0)" ::: "memory");
    asm volatile("s_barrier" ::: "memory");
  }

#pragma unroll
  for (int mt = 0; mt < 2; ++mt) {
    float inv = 1.f / l_i[mt];
    int s = q0 + wave * 32 + mt * 16 + ln;
    size_t rowbase = ((size_t)b * SEQ + s) * (NH * VD) + h * VD;
#pragma unroll
    for (int dt = 0; dt < 8; ++dt) {
      ushort4 pk;
      pk.x = f2bf(o[mt][dt][0] * inv);
      pk.y = f2bf(o[mt][dt][1] * inv);
      pk.z = f2bf(o[mt][dt][2] * inv);
      pk.w = f2bf(o[mt][dt][3] * inv);
      *(ushort4*)&O[rowbase + dt * 16 + quad * 4] = pk;
    }
  }
}

extern "C" void kernel_launch(void* const* d_in, const int* in_sizes, int n_in,
                              void* d_out, int out_size, void* d_ws, size_t ws_size,
                              hipStream_t stream) {
  const float* x_f    = (const float*)d_in[0];
  const float* qaw_f  = (const float*)d_in[1];
  const float* qbw_f  = (const float*)d_in[2];
  const float* kvaw_f = (const float*)d_in[3];
  const float* kvbw_f = (const float*)d_in[4];
  const float* ow_f   = (const float*)d_in[5];

  char* ws = (char*)d_ws;
  size_t off = 0;
  auto alloc = [&](size_t n) {
    unsigned short* p = (unsigned short*)(ws + off);
    off = (off + n * 2 + 255) & ~(size_t)255;
    return p;
  };
  unsigned short* Xb    = alloc((size_t)BS * EMB);
  unsigned short* Wcomb = alloc((size_t)NCOMB * EMB);
  unsigned short* Wqb   = alloc((size_t)(NH * QKD) * QRANK);
  unsigned short* Wkvb  = alloc((size_t)(NH * 192) * KVRANK);
  unsigned short* Wo    = alloc((size_t)EMB * (NH * VD));
  unsigned short* CQKV  = alloc((size_t)BS * NCOMB);
  unsigned short* KVB   = alloc((size_t)BS * (NH * 192));
  unsigned short* Qry   = alloc((size_t)BHD * SEQ * QKD);
  unsigned short* Key   = alloc((size_t)BHD * SEQ * QKD);
  unsigned short* Vt    = alloc((size_t)BHD * VD * SEQ);
  unsigned short* AO    = alloc((size_t)BS * (NH * VD));

  cast_all<<<dim3(8192), 256, 0, stream>>>(x_f, qaw_f, kvaw_f, qbw_f, kvbw_f, ow_f,
                                           Xb, Wcomb, Wqb, Wkvb, Wo);

  // [cq | ckv | rope(raw)] = x @ [q_a_w; kv_a_w]^T  (4096 x 2112, K=2048)
  gemm_bt<0><<<dim3((NCOMB + 127) / 128, BS / 128), 256, 0, stream>>>(
      Xb, EMB, Wcomb, EMB, CQKV, BS, NCOMB, EMB);
  // q = cq @ q_b_w^T, RoPE + log2e + permuted store (4096 x 2048, K=1536)
  gemm_q_rope<<<dim3((NH * QKD) / 128, BS / 128), 256, 0, stream>>>(
      CQKV, NCOMB, Wqb, QRANK, Qry, QRANK);
  // kvb = ckv @ kv_b_w^T (4096 x 3072, K=512)
  gemm_bt<0><<<dim3((NH * 192) / 128, BS / 128), 256, 0, stream>>>(
      CQKV + QRANK, NCOMB, Wkvb, KVRANK, KVB, BS, NH * 192, KVRANK);

  // fused Key + V^T prep (one KVB pass, one launch)
  prep_kv<<<dim3(BHD * (SEQ / 64)), 256, 0, stream>>>(KVB, CQKV, Key, Vt);

  flash_attn<<<dim3(BHD, SEQ / 128), 256, 0, stream>>>(Qry, Key, Vt, AO);

  // out = AO @ o_w^T (fp32 out)
  gemm_bt<1><<<dim3(EMB / 128, BS / 128), 256, 0, stream>>>(
      AO, NH * VD, Wo, NH * VD, d_out, BS, EMB, NH * VD);
}

// Round 6
// 387.378 us; speedup vs baseline: 1.0515x; 1.0515x over previous
//
#include <hip/hip_runtime.h>
#include <stdint.h>

#define EMB 2048
#define NH 16
#define QRANK 1536
#define KVRANK 512
#define ROPED 64
#define NOPED 64
#define VD 128
#define QKD 128
#define SEQ 2048
#define BATCH 2
#define BS 4096            // BATCH*SEQ
#define BHD 32             // BATCH*NH
#define NCOMB 2112         // QRANK + KVRANK + ROPED
#define LOG2E 1.4426950408889634f
#define NT (SEQ / 64)      // 32 KV tiles

typedef __attribute__((ext_vector_type(4))) float f32x4;
typedef __attribute__((ext_vector_type(8))) short s16x8;
typedef __attribute__((ext_vector_type(4))) short s16x4;
typedef __attribute__((ext_vector_type(2))) unsigned int u32x2;

__device__ __forceinline__ float bf2f(unsigned short u) {
  return __uint_as_float(((unsigned int)u) << 16);
}
__device__ __forceinline__ unsigned short f2bf(float f) {
  unsigned int u = __float_as_uint(f);
  u += 0x7fff + ((u >> 16) & 1);
  return (unsigned short)(u >> 16);
}

__device__ __forceinline__ float vexp2(float x) {
#if __has_builtin(__builtin_amdgcn_exp2f)
  return __builtin_amdgcn_exp2f(x);
#else
  return exp2f(x);
#endif
}

// pack hi16(e1):hi16(e0) into one dword (bf16 truncation)
__device__ __forceinline__ unsigned int pk_bf16_trunc(float e0, float e1) {
#if __has_builtin(__builtin_amdgcn_perm)
  return __builtin_amdgcn_perm(__float_as_uint(e1), __float_as_uint(e0), 0x07060302u);
#else
  return (__float_as_uint(e1) & 0xffff0000u) | (__float_as_uint(e0) >> 16);
#endif
}

// CDNA4 lane-row swaps (both outputs used).
__device__ __forceinline__ void pl32swap(unsigned int& a, unsigned int& b) {
#if __has_builtin(__builtin_amdgcn_permlane32_swap)
  u32x2 r = __builtin_amdgcn_permlane32_swap(a, b, false, false);
  a = r.x; b = r.y;
#else
  asm("v_permlane32_swap_b32 %0, %1" : "+v"(a), "+v"(b));
#endif
}
__device__ __forceinline__ void pl16swap(unsigned int& a, unsigned int& b) {
#if __has_builtin(__builtin_amdgcn_permlane16_swap)
  u32x2 r = __builtin_amdgcn_permlane16_swap(a, b, false, false);
  a = r.x; b = r.y;
#else
  asm("v_permlane16_swap_b32 %0, %1" : "+v"(a), "+v"(b));
#endif
}

__device__ __forceinline__ void gld_lds16(const unsigned short* g, unsigned short* l) {
  __builtin_amdgcn_global_load_lds((const __attribute__((address_space(1))) void*)g,
                                   (__attribute__((address_space(3))) void*)l,
                                   16, 0, 0);
}

// ---------------- fused cast f32 -> bf16, all 6 tensors, one launch ----------
#define N4_X   (BS * EMB / 4)
#define N4_QA  (QRANK * EMB / 4)
#define N4_KVA ((KVRANK + ROPED) * EMB / 4)
#define N4_QB  (NH * QKD * QRANK / 4)
#define N4_KVB (NH * 192 * KVRANK / 4)
#define N4_O   (EMB * NH * VD / 4)
#define N4_TOT (N4_X + N4_QA + N4_KVA + N4_QB + N4_KVB + N4_O)

__global__ void cast_all(const float* __restrict__ x, const float* __restrict__ qa,
                         const float* __restrict__ kva, const float* __restrict__ qb,
                         const float* __restrict__ kvb, const float* __restrict__ ow,
                         unsigned short* __restrict__ Xb, unsigned short* __restrict__ Wcomb,
                         unsigned short* __restrict__ Wqb, unsigned short* __restrict__ Wkvb,
                         unsigned short* __restrict__ Wo) {
  int i = blockIdx.x * blockDim.x + threadIdx.x;
  int stride = gridDim.x * blockDim.x;
  for (; i < N4_TOT; i += stride) {
    const float4* src;
    ushort4* dst;
    int j = i;
    if (j < N4_X) { src = (const float4*)x; dst = (ushort4*)Xb; }
    else if ((j -= N4_X) < N4_QA) { src = (const float4*)qa; dst = (ushort4*)Wcomb; }
    else if ((j -= N4_QA) < N4_KVA) { src = (const float4*)kva; dst = (ushort4*)(Wcomb + (size_t)QRANK * EMB); }
    else if ((j -= N4_KVA) < N4_QB) { src = (const float4*)qb; dst = (ushort4*)Wqb; }
    else if ((j -= N4_QB) < N4_KVB) { src = (const float4*)kvb; dst = (ushort4*)Wkvb; }
    else { j -= N4_KVB; src = (const float4*)ow; dst = (ushort4*)Wo; }
    float4 v = src[j];
    ushort4 o;
    o.x = f2bf(v.x); o.y = f2bf(v.y); o.z = f2bf(v.z); o.w = f2bf(v.w);
    dst[j] = o;
  }
}

// ---------------- GEMM v2: dbuf LDS + counted vmcnt (flash-v8 schedule) ------
// C[M,N] = A[M,K(lda)] * W[N,K(ldw)]^T. 128x128 tile, BK=64, 4 waves 2x2.
// v1 staged tile t then IMMEDIATELY drained it (__syncthreads => vmcnt(0)) --
// every K-step serially ate full L2/L3 latency. v2: stage(t+1) issues BEFORE
// waiting on t (vmcnt(8) keeps t+1's 8 loads in flight through t's compute);
// raw s_barrier pair (RAW rendezvous / WAR before re-staging buf[t&1]).
template <int OUT_F32>
__global__ __launch_bounds__(256, 2) void gemm_bt(
    const unsigned short* __restrict__ A, int lda,
    const unsigned short* __restrict__ W, int ldw,
    void* __restrict__ C, int M, int N, int K)
{
  __shared__ __align__(16) unsigned short As[2][128 * 64];
  __shared__ __align__(16) unsigned short Ws[2][128 * 64];
  const int tid = threadIdx.x;
  const int wave = tid >> 6;
  const int lane = tid & 63;
  const int ln = lane & 15;
  const int quad = lane >> 4;
  const int bm = blockIdx.y * 128;
  const int bn = blockIdx.x * 128;
  const int wm = (wave >> 1) * 64;
  const int wn = (wave & 1) * 64;

  f32x4 acc[4][4] = {};

  const int rel8 = lane >> 3;
  const int csw = ((lane & 7) ^ rel8) * 8;

  auto stage = [&](int buf, int k0) {
#pragma unroll
    for (int it = 0; it < 4; ++it) {
      int rb = wave * 32 + it * 8;
      gld_lds16(A + (size_t)(bm + rb + rel8) * lda + k0 + csw, &As[buf][rb * 64]);
    }
#pragma unroll
    for (int it = 0; it < 4; ++it) {
      int rb = wave * 32 + it * 8;
      int wr = bn + rb + rel8;
      if (wr >= N) wr = N - 1;
      gld_lds16(W + (size_t)wr * ldw + k0 + csw, &Ws[buf][rb * 64]);
    }
  };

  const int KT = K >> 6;
  stage(0, 0);
  for (int t = 0; t < KT; ++t) {
    if (t + 1 < KT) {
      stage((t + 1) & 1, (t + 1) << 6);
      asm volatile("s_waitcnt vmcnt(8)" ::: "memory");   // tile t's loads done
    } else {
      asm volatile("s_waitcnt vmcnt(0)" ::: "memory");
    }
    asm volatile("s_barrier" ::: "memory");              // RAW: t staged for all
    const unsigned short* Ac = As[t & 1];
    const unsigned short* Wc = Ws[t & 1];
#pragma unroll
    for (int kk = 0; kk < 64; kk += 32) {
      s16x8 a[4], b[4];
#pragma unroll
      for (int mt = 0; mt < 4; ++mt)
        a[mt] = *(const s16x8*)&Ac[(wm + mt * 16 + ln) * 64 + ((kk / 8 + quad) ^ (ln & 7)) * 8];
#pragma unroll
      for (int nt = 0; nt < 4; ++nt)
        b[nt] = *(const s16x8*)&Wc[(wn + nt * 16 + ln) * 64 + ((kk / 8 + quad) ^ (ln & 7)) * 8];
#pragma unroll
      for (int mt = 0; mt < 4; ++mt)
#pragma unroll
        for (int nt = 0; nt < 4; ++nt)
          acc[mt][nt] = __builtin_amdgcn_mfma_f32_16x16x32_bf16(a[mt], b[nt], acc[mt][nt], 0, 0, 0);
    }
    asm volatile("s_barrier" ::: "memory");              // WAR: buf[t&1] free
  }
#pragma unroll
  for (int mt = 0; mt < 4; ++mt) {
    int row = bm + wm + mt * 16 + quad * 4;
#pragma unroll
    for (int nt = 0; nt < 4; ++nt) {
      int col = bn + wn + nt * 16 + ln;
      if (col < N) {
#pragma unroll
        for (int r = 0; r < 4; ++r) {
          float v = acc[mt][nt][r];
          if (OUT_F32)
            ((float*)C)[(size_t)(row + r) * N + col] = v;
          else
            ((unsigned short*)C)[(size_t)(row + r) * N + col] = f2bf(v);
        }
      }
    }
  }
}

// ---------------- q GEMM v2: same dbuf schedule + fused RoPE epilogue --------
__global__ __launch_bounds__(256, 2) void gemm_q_rope(
    const unsigned short* __restrict__ A, int lda,
    const unsigned short* __restrict__ W, int ldw,
    unsigned short* __restrict__ Qry, int K)
{
  __shared__ __align__(16) unsigned short As[2][128 * 64];
  __shared__ __align__(16) unsigned short Ws[2][128 * 64];
  const int tid = threadIdx.x;
  const int wave = tid >> 6;
  const int lane = tid & 63;
  const int ln = lane & 15;
  const int quad = lane >> 4;
  const int bm = blockIdx.y * 128;
  const int bn = blockIdx.x * 128;
  const int wm = (wave >> 1) * 64;
  const int wn = (wave & 1) * 64;

  f32x4 acc[4][4] = {};
  const int rel8 = lane >> 3;
  const int csw = ((lane & 7) ^ rel8) * 8;

  auto stage = [&](int buf, int k0) {
#pragma unroll
    for (int it = 0; it < 4; ++it) {
      int rb = wave * 32 + it * 8;
      gld_lds16(A + (size_t)(bm + rb + rel8) * lda + k0 + csw, &As[buf][rb * 64]);
    }
#pragma unroll
    for (int it = 0; it < 4; ++it) {
      int rb = wave * 32 + it * 8;
      gld_lds16(W + (size_t)(bn + rb + rel8) * ldw + k0 + csw, &Ws[buf][rb * 64]);
    }
  };

  const int KT = K >> 6;
  stage(0, 0);
  for (int t = 0; t < KT; ++t) {
    if (t + 1 < KT) {
      stage((t + 1) & 1, (t + 1) << 6);
      asm volatile("s_waitcnt vmcnt(8)" ::: "memory");
    } else {
      asm volatile("s_waitcnt vmcnt(0)" ::: "memory");
    }
    asm volatile("s_barrier" ::: "memory");
    const unsigned short* Ac = As[t & 1];
    const unsigned short* Wc = Ws[t & 1];
#pragma unroll
    for (int kk = 0; kk < 64; kk += 32) {
      s16x8 a[4], b[4];
#pragma unroll
      for (int mt = 0; mt < 4; ++mt)
        a[mt] = *(const s16x8*)&Ac[(wm + mt * 16 + ln) * 64 + ((kk / 8 + quad) ^ (ln & 7)) * 8];
#pragma unroll
      for (int nt = 0; nt < 4; ++nt)
        b[nt] = *(const s16x8*)&Wc[(wn + nt * 16 + ln) * 64 + ((kk / 8 + quad) ^ (ln & 7)) * 8];
#pragma unroll
      for (int mt = 0; mt < 4; ++mt)
#pragma unroll
        for (int nt = 0; nt < 4; ++nt)
          acc[mt][nt] = __builtin_amdgcn_mfma_f32_16x16x32_bf16(a[mt], b[nt], acc[mt][nt], 0, 0, 0);
    }
    asm volatile("s_barrier" ::: "memory");
  }
  const bool odd = (ln & 1);
#pragma unroll
  for (int mt = 0; mt < 4; ++mt) {
    int rowb = bm + wm + mt * 16 + quad * 4;
#pragma unroll
    for (int nt = 0; nt < 4; ++nt) {
      int col = bn + wn + nt * 16 + ln;
      int h = col >> 7, d = col & 127;
#pragma unroll
      for (int r = 0; r < 4; ++r) {
        float v = acc[mt][nt][r];
        float other = __shfl_xor(v, 1);
        int row = rowb + r;
        int b = row >> 11, s = row & 2047;
        float y = v;
        if (d >= NOPED) {
          int i = (d - NOPED) >> 1;
          float theta = exp2f(-(float)i * (13.287712379549449f / 32.f));
          float ang = (float)s * theta;
          float sn, c;
          sincosf(ang, &sn, &c);
          y = v * c + (odd ? other * sn : -other * sn);
        }
        y *= LOG2E;   // fold softmax exp->exp2 conversion into Q
        Qry[((size_t)(b * NH + h) * SEQ + s) * QKD + d] = f2bf(y);
      }
    }
  }
}

// ---------------- fused prep: Key (nope + RoPE) AND V^T, one KVB pass --------
__global__ void prep_kv(const unsigned short* __restrict__ kvb,
                        const unsigned short* __restrict__ cqkv,
                        unsigned short* __restrict__ Key,
                        unsigned short* __restrict__ VT) {
  __shared__ unsigned short vt[64][132];
  __shared__ unsigned short kr[64][64];
  int blk = blockIdx.x;
  int bh = blk >> 5, st = blk & 31;
  int b = bh >> 4, h = bh & 15;
  int s0 = st * 64;
  int tid = threadIdx.x;

  // krot: 64 rows x 32 pairs
  for (int idx = tid; idx < 64 * 32; idx += 256) {
    int sl = idx >> 5, i = idx & 31;
    int s = s0 + sl;
    const unsigned short* rp = cqkv + (size_t)(b * SEQ + s) * NCOMB + QRANK + KVRANK;
    float x0 = bf2f(rp[2 * i]);
    float x1 = bf2f(rp[2 * i + 1]);
    float theta = exp2f(-(float)i * (13.287712379549449f / 32.f));
    float ang = (float)s * theta;
    float sn, c;
    sincosf(ang, &sn, &c);
    kr[sl][2 * i] = f2bf(x0 * c - x1 * sn);
    kr[sl][2 * i + 1] = f2bf(x1 * c + x0 * sn);
  }
  // V tile load (16B vectors)
  for (int idx = tid; idx < 64 * 16; idx += 256) {
    int sl = idx >> 4, dc = idx & 15;
    s16x8 v = *(const s16x8*)(kvb + (size_t)(b * SEQ + s0 + sl) * (NH * 192) + h * 192 + NOPED + dc * 8);
    *(s16x8*)&vt[sl][dc * 8] = v;
  }
  __syncthreads();
  // Key write: d<64 nope straight from kvb, d>=64 from kr
  for (int idx = tid; idx < 64 * 128; idx += 256) {
    int sl = idx >> 7, d = idx & 127;
    unsigned short v;
    if (d < NOPED)
      v = kvb[(size_t)(b * SEQ + s0 + sl) * (NH * 192) + h * 192 + d];
    else
      v = kr[sl][d - NOPED];
    Key[((size_t)bh * SEQ + s0 + sl) * QKD + d] = v;
  }
  // V^T write
  for (int idx = tid; idx < 64 * 128; idx += 256) {
    int d = idx >> 6, sl = idx & 63;
    VT[((size_t)bh * VD + d) * SEQ + s0 + sl] = vt[sl][d];
  }
}

// ---------------- flash attention v10 (reverted): cross-tile pipeline --------
// v11 (3-blocks/CU attempt) regressed 86.6->114.7us: grid is 512 blocks = 2/CU
// (grid-limited, occupancy stayed 20%) and single-buffered K serialized the
// QK->stage chain. v10 was the measured best (86.6us); restored verbatim.
__global__ __launch_bounds__(256, 2) void flash_attn(
    const unsigned short* __restrict__ Q,
    const unsigned short* __restrict__ Kt,     // (BHD, SEQ, 128)
    const unsigned short* __restrict__ VT,     // (BHD, 128, SEQ)
    unsigned short* __restrict__ O)
{
  __shared__ __align__(16) unsigned short Ks[2][64 * 128];
  __shared__ __align__(16) unsigned short Vs[3][128 * 64];

  const int tid = threadIdx.x;
  const int wave = tid >> 6;
  const int lane = tid & 63;
  const int ln = lane & 15;
  const int quad = lane >> 4;
  const int bh = blockIdx.x;
  const int q0 = blockIdx.y * 128;
  const int b = bh >> 4, h = bh & 15;

  // ---- Q fragments straight from global (B-operand of S^T = K·Q^T)
  s16x8 qa[2][4];
#pragma unroll
  for (int mt = 0; mt < 2; ++mt) {
    const unsigned short* qrow = Q + ((size_t)bh * SEQ + q0 + wave * 32 + mt * 16 + ln) * QKD;
#pragma unroll
    for (int kx = 0; kx < 4; ++kx)
      qa[mt][kx] = *(const s16x8*)(qrow + kx * 32 + quad * 8);
  }

  const int krel = lane >> 4, kcch = lane & 15;
  const int vrel8 = lane >> 3;
  const int vc8 = (lane & 7) ^ vrel8;

  // 8 async loads per wave per tile (4 K + 4 V); tile t -> Ks[t&1], Vs[t%3]
  auto stage = [&](unsigned short* Kd, unsigned short* Vd, int kt) {
#pragma unroll
    for (int it = 0; it < 4; ++it) {
      int rb = wave * 16 + it * 4;
      int rr = rb + krel;
      int c = kcch ^ (rr & 15);
      gld_lds16(Kt + ((size_t)bh * SEQ + kt * 64 + rr) * QKD + c * 8, Kd + rb * 128);
    }
#pragma unroll
    for (int it = 0; it < 4; ++it) {
      int rb = wave * 32 + it * 8;
      gld_lds16(VT + ((size_t)bh * VD + rb + vrel8) * SEQ + kt * 64 + vc8 * 8, Vd + rb * 64);
    }
  };

  f32x4 o[2][8] = {};              // o[mt][dt]: d = dt*16+quad*4+r, q = mt*16+ln
  float l_i[2] = {0.f, 0.f};

  // ---- chunk helpers (all inlined; call sites use literal args)
  auto sc_init = [&](f32x4 (&sc)[2][4]) {
#pragma unroll
    for (int mt = 0; mt < 2; ++mt)
#pragma unroll
      for (int t = 0; t < 4; ++t)
        sc[mt][t] = (f32x4){-20.f, -20.f, -20.f, -20.f};
  };
  auto qk_kx = [&](int kx, const unsigned short* Kc, f32x4 (&sc)[2][4]) {
    s16x8 ak[4];
#pragma unroll
    for (int t = 0; t < 4; ++t)
      ak[t] = *(const s16x8*)&Kc[(t * 16 + ln) * 128 + ((kx * 4 + quad) ^ ln) * 8];
#pragma unroll
    for (int mt = 0; mt < 2; ++mt)
#pragma unroll
      for (int t = 0; t < 4; ++t)
        sc[mt][t] = __builtin_amdgcn_mfma_f32_16x16x32_bf16(ak[t], qa[mt][kx], sc[mt][t], 0, 0, 0);
  };
  auto sm_mt = [&](int mt, f32x4 (&sc)[2][4], s16x8 (&pfrag)[2][2]) {
    float rs = 0.f;
    unsigned int pw[4][2];
#pragma unroll
    for (int t = 0; t < 4; ++t) {
      float e0 = vexp2(sc[mt][t][0]);
      float e1 = vexp2(sc[mt][t][1]);
      float e2 = vexp2(sc[mt][t][2]);
      float e3 = vexp2(sc[mt][t][3]);
      unsigned int p01 = pk_bf16_trunc(e0, e1);
      unsigned int p23 = pk_bf16_trunc(e2, e3);
      pw[t][0] = p01; pw[t][1] = p23;
      rs += (__uint_as_float(p01 << 16) + __uint_as_float(p01 & 0xffff0000u))
          + (__uint_as_float(p23 << 16) + __uint_as_float(p23 & 0xffff0000u));
    }
    rs += __shfl_xor(rs, 16);
    rs += __shfl_xor(rs, 32);
    l_i[mt] += rs;
#pragma unroll
    for (int W = 0; W < 2; ++W) {
      unsigned int u0 = pw[2 * W][0], v0 = pw[2 * W + 1][0];
      unsigned int u1 = pw[2 * W][1], v1 = pw[2 * W + 1][1];
      pl32swap(u0, v0); pl16swap(u0, v0);
      pl32swap(u1, v1); pl16swap(u1, v1);
      union { unsigned int u[4]; s16x8 v; } fb;
      fb.u[0] = u0;    // k_local = quad*8 + {0,1}
      fb.u[1] = u1;    // k_local = quad*8 + {2,3}
      fb.u[2] = v0;    // k_local = quad*8 + {4,5}
      fb.u[3] = v1;    // k_local = quad*8 + {6,7}
      pfrag[mt][W] = fb.v;
    }
  };
  auto pv_half = [&](int half, const unsigned short* Vc, s16x8 (&pfrag)[2][2]) {
#pragma unroll
    for (int dd = 0; dd < 4; ++dd) {
      int dt = half * 4 + dd;
      s16x8 av0 = *(const s16x8*)&Vc[(dt * 16 + ln) * 64 + ((quad ^ (ln & 7)) * 8)];
      s16x8 av1 = *(const s16x8*)&Vc[(dt * 16 + ln) * 64 + (((4 + quad) ^ (ln & 7)) * 8)];
#pragma unroll
      for (int mt = 0; mt < 2; ++mt) {
        o[mt][dt] = __builtin_amdgcn_mfma_f32_16x16x32_bf16(av0, pfrag[mt][0], o[mt][dt], 0, 0, 0);
        o[mt][dt] = __builtin_amdgcn_mfma_f32_16x16x32_bf16(av1, pfrag[mt][1], o[mt][dt], 0, 0, 0);
      }
    }
  };

  // ---- pipelined iteration: QK(kt)->scC interleaved with softmax+PV(kt-1)
  auto iter = [&](int kt, f32x4 (&scP)[2][4], f32x4 (&scC)[2][4]) {
    asm volatile("s_waitcnt vmcnt(0)" ::: "memory");     // tile kt staged
    asm volatile("s_barrier" ::: "memory");              // all reads of (kt+1)-buffers done
    if (kt + 1 < NT)
      stage(Ks[(kt + 1) & 1], Vs[(kt + 1) % 3], kt + 1);
    const unsigned short* Kc = Ks[kt & 1];
    const unsigned short* Vp = Vs[(kt - 1) % 3];
    s16x8 pfrag[2][2];
    __builtin_amdgcn_s_setprio(1);
    sc_init(scC);
    qk_kx(0, Kc, scC);
    sm_mt(0, scP, pfrag);
    qk_kx(1, Kc, scC);
    sm_mt(1, scP, pfrag);
    qk_kx(2, Kc, scC);
    pv_half(0, Vp, pfrag);
    qk_kx(3, Kc, scC);
    pv_half(1, Vp, pfrag);
    __builtin_amdgcn_s_setprio(0);
  };

  f32x4 scA[2][4], scB[2][4];

  // prologue: stage tiles 0 and 1; QK(0) -> scA
  stage(Ks[0], Vs[0], 0);
  asm volatile("s_waitcnt vmcnt(0)" ::: "memory");
  asm volatile("s_barrier" ::: "memory");
  stage(Ks[1], Vs[1], 1);
  __builtin_amdgcn_s_setprio(1);
  sc_init(scA);
  qk_kx(0, Ks[0], scA);
  qk_kx(1, Ks[0], scA);
  qk_kx(2, Ks[0], scA);
  qk_kx(3, Ks[0], scA);
  __builtin_amdgcn_s_setprio(0);

  // 15 pairs cover kt = 1..30 with static sc ping-pong
  int kt = 1;
#pragma unroll 1
  for (int p = 0; p < 15; ++p, kt += 2) {
    iter(kt, scA, scB);
    iter(kt + 1, scB, scA);
  }
  iter(31, scA, scB);

  // epilogue: softmax+PV for tile 31 (V in Vs[31 % 3] = Vs[1])
  {
    s16x8 pfrag[2][2];
    sm_mt(0, scB, pfrag);
    sm_mt(1, scB, pfrag);
    pv_half(0, Vs[1], pfrag);
    pv_half(1, Vs[1], pfrag);
  }

#pragma unroll
  for (int mt = 0; mt < 2; ++mt) {
    float inv = 1.f / l_i[mt];
    int s = q0 + wave * 32 + mt * 16 + ln;
    size_t rowbase = ((size_t)b * SEQ + s) * (NH * VD) + h * VD;
#pragma unroll
    for (int dt = 0; dt < 8; ++dt) {
      ushort4 pk;
      pk.x = f2bf(o[mt][dt][0] * inv);
      pk.y = f2bf(o[mt][dt][1] * inv);
      pk.z = f2bf(o[mt][dt][2] * inv);
      pk.w = f2bf(o[mt][dt][3] * inv);
      *(ushort4*)&O[rowbase + dt * 16 + quad * 4] = pk;
    }
  }
}

extern "C" void kernel_launch(void* const* d_in, const int* in_sizes, int n_in,
                              void* d_out, int out_size, void* d_ws, size_t ws_size,
                              hipStream_t stream) {
  const float* x_f    = (const float*)d_in[0];
  const float* qaw_f  = (const float*)d_in[1];
  const float* qbw_f  = (const float*)d_in[2];
  const float* kvaw_f = (const float*)d_in[3];
  const float* kvbw_f = (const float*)d_in[4];
  const float* ow_f   = (const float*)d_in[5];

  char* ws = (char*)d_ws;
  size_t off = 0;
  auto alloc = [&](size_t n) {
    unsigned short* p = (unsigned short*)(ws + off);
    off = (off + n * 2 + 255) & ~(size_t)255;
    return p;
  };
  unsigned short* Xb    = alloc((size_t)BS * EMB);
  unsigned short* Wcomb = alloc((size_t)NCOMB * EMB);
  unsigned short* Wqb   = alloc((size_t)(NH * QKD) * QRANK);
  unsigned short* Wkvb  = alloc((size_t)(NH * 192) * KVRANK);
  unsigned short* Wo    = alloc((size_t)EMB * (NH * VD));
  unsigned short* CQKV  = alloc((size_t)BS * NCOMB);
  unsigned short* KVB   = alloc((size_t)BS * (NH * 192));
  unsigned short* Qry   = alloc((size_t)BHD * SEQ * QKD);
  unsigned short* Key   = alloc((size_t)BHD * SEQ * QKD);
  unsigned short* Vt    = alloc((size_t)BHD * VD * SEQ);
  unsigned short* AO    = alloc((size_t)BS * (NH * VD));

  cast_all<<<dim3(8192), 256, 0, stream>>>(x_f, qaw_f, kvaw_f, qbw_f, kvbw_f, ow_f,
                                           Xb, Wcomb, Wqb, Wkvb, Wo);

  // [cq | ckv | rope(raw)] = x @ [q_a_w; kv_a_w]^T  (4096 x 2112, K=2048)
  gemm_bt<0><<<dim3((NCOMB + 127) / 128, BS / 128), 256, 0, stream>>>(
      Xb, EMB, Wcomb, EMB, CQKV, BS, NCOMB, EMB);
  // q = cq @ q_b_w^T, RoPE + log2e + permuted store (4096 x 2048, K=1536)
  gemm_q_rope<<<dim3((NH * QKD) / 128, BS / 128), 256, 0, stream>>>(
      CQKV, NCOMB, Wqb, QRANK, Qry, QRANK);
  // kvb = ckv @ kv_b_w^T (4096 x 3072, K=512)
  gemm_bt<0><<<dim3((NH * 192) / 128, BS / 128), 256, 0, stream>>>(
      CQKV + QRANK, NCOMB, Wkvb, KVRANK, KVB, BS, NH * 192, KVRANK);

  // fused Key + V^T prep (one KVB pass, one launch)
  prep_kv<<<dim3(BHD * (SEQ / 64)), 256, 0, stream>>>(KVB, CQKV, Key, Vt);

  flash_attn<<<dim3(BHD, SEQ / 128), 256, 0, stream>>>(Qry, Key, Vt, AO);

  // out = AO @ o_w^T (fp32 out)
  gemm_bt<1><<<dim3(EMB / 128, BS / 128), 256, 0, stream>>>(
      AO, NH * VD, Wo, NH * VD, d_out, BS, EMB, NH * VD);
}

// Round 7
// 374.757 us; speedup vs baseline: 1.0869x; 1.0337x over previous
//
#include <hip/hip_runtime.h>
#include <stdint.h>

#define EMB 2048
#define NH 16
#define QRANK 1536
#define KVRANK 512
#define ROPED 64
#define NOPED 64
#define VD 128
#define QKD 128
#define SEQ 2048
#define BATCH 2
#define BS 4096            // BATCH*SEQ
#define BHD 32             // BATCH*NH
#define NCOMB 2112         // QRANK + KVRANK + ROPED
#define LOG2E 1.4426950408889634f
#define NT (SEQ / 64)      // 32 KV tiles

typedef __attribute__((ext_vector_type(4))) float f32x4;
typedef __attribute__((ext_vector_type(8))) short s16x8;
typedef __attribute__((ext_vector_type(4))) short s16x4;
typedef __attribute__((ext_vector_type(2))) unsigned int u32x2;

__device__ __forceinline__ float bf2f(unsigned short u) {
  return __uint_as_float(((unsigned int)u) << 16);
}
__device__ __forceinline__ unsigned short f2bf(float f) {
  unsigned int u = __float_as_uint(f);
  u += 0x7fff + ((u >> 16) & 1);
  return (unsigned short)(u >> 16);
}

__device__ __forceinline__ float vexp2(float x) {
#if __has_builtin(__builtin_amdgcn_exp2f)
  return __builtin_amdgcn_exp2f(x);
#else
  return exp2f(x);
#endif
}

// pack hi16(e1):hi16(e0) into one dword (bf16 truncation)
__device__ __forceinline__ unsigned int pk_bf16_trunc(float e0, float e1) {
#if __has_builtin(__builtin_amdgcn_perm)
  return __builtin_amdgcn_perm(__float_as_uint(e1), __float_as_uint(e0), 0x07060302u);
#else
  return (__float_as_uint(e1) & 0xffff0000u) | (__float_as_uint(e0) >> 16);
#endif
}

// CDNA4 lane-row swaps (both outputs used).
__device__ __forceinline__ void pl32swap(unsigned int& a, unsigned int& b) {
#if __has_builtin(__builtin_amdgcn_permlane32_swap)
  u32x2 r = __builtin_amdgcn_permlane32_swap(a, b, false, false);
  a = r.x; b = r.y;
#else
  asm("v_permlane32_swap_b32 %0, %1" : "+v"(a), "+v"(b));
#endif
}
__device__ __forceinline__ void pl16swap(unsigned int& a, unsigned int& b) {
#if __has_builtin(__builtin_amdgcn_permlane16_swap)
  u32x2 r = __builtin_amdgcn_permlane16_swap(a, b, false, false);
  a = r.x; b = r.y;
#else
  asm("v_permlane16_swap_b32 %0, %1" : "+v"(a), "+v"(b));
#endif
}

__device__ __forceinline__ void gld_lds16(const unsigned short* g, unsigned short* l) {
  __builtin_amdgcn_global_load_lds((const __attribute__((address_space(1))) void*)g,
                                   (__attribute__((address_space(3))) void*)l,
                                   16, 0, 0);
}

// ---------------- fused cast f32 -> bf16, all 6 tensors, one launch ----------
#define N4_X   (BS * EMB / 4)
#define N4_QA  (QRANK * EMB / 4)
#define N4_KVA ((KVRANK + ROPED) * EMB / 4)
#define N4_QB  (NH * QKD * QRANK / 4)
#define N4_KVB (NH * 192 * KVRANK / 4)
#define N4_O   (EMB * NH * VD / 4)
#define N4_TOT (N4_X + N4_QA + N4_KVA + N4_QB + N4_KVB + N4_O)

__global__ void cast_all(const float* __restrict__ x, const float* __restrict__ qa,
                         const float* __restrict__ kva, const float* __restrict__ qb,
                         const float* __restrict__ kvb, const float* __restrict__ ow,
                         unsigned short* __restrict__ Xb, unsigned short* __restrict__ Wcomb,
                         unsigned short* __restrict__ Wqb, unsigned short* __restrict__ Wkvb,
                         unsigned short* __restrict__ Wo) {
  int i = blockIdx.x * blockDim.x + threadIdx.x;
  int stride = gridDim.x * blockDim.x;
  for (; i < N4_TOT; i += stride) {
    const float4* src;
    ushort4* dst;
    int j = i;
    if (j < N4_X) { src = (const float4*)x; dst = (ushort4*)Xb; }
    else if ((j -= N4_X) < N4_QA) { src = (const float4*)qa; dst = (ushort4*)Wcomb; }
    else if ((j -= N4_QA) < N4_KVA) { src = (const float4*)kva; dst = (ushort4*)(Wcomb + (size_t)QRANK * EMB); }
    else if ((j -= N4_KVA) < N4_QB) { src = (const float4*)qb; dst = (ushort4*)Wqb; }
    else if ((j -= N4_QB) < N4_KVB) { src = (const float4*)kvb; dst = (ushort4*)Wkvb; }
    else { j -= N4_KVB; src = (const float4*)ow; dst = (ushort4*)Wo; }
    float4 v = src[j];
    ushort4 o;
    o.x = f2bf(v.x); o.y = f2bf(v.y); o.z = f2bf(v.z); o.w = f2bf(v.w);
    dst[j] = o;
  }
}

// ---------------- GEMM v1 (restored): C[M,N] = A[M,K] * W[N,K]^T ------------
// v2 (dbuf 64KB + counted vmcnt) regressed ~10us total: LDS doubling halved
// occupancy 4->2 blocks/CU; implicit cross-block overlap beats explicit dbuf
// at this tile size (matches m99-m140). v1 restored verbatim.
template <int OUT_F32>
__global__ __launch_bounds__(256, 2) void gemm_bt(
    const unsigned short* __restrict__ A, int lda,
    const unsigned short* __restrict__ W, int ldw,
    void* __restrict__ C, int M, int N, int K)
{
  __shared__ __align__(16) unsigned short As[128 * 64];
  __shared__ __align__(16) unsigned short Ws[128 * 64];
  const int tid = threadIdx.x;
  const int wave = tid >> 6;
  const int lane = tid & 63;
  const int ln = lane & 15;
  const int quad = lane >> 4;
  const int bm = blockIdx.y * 128;
  const int bn = blockIdx.x * 128;
  const int wm = (wave >> 1) * 64;
  const int wn = (wave & 1) * 64;

  f32x4 acc[4][4] = {};

  const int rel8 = lane >> 3;
  const int csw = ((lane & 7) ^ rel8) * 8;

  for (int k0 = 0; k0 < K; k0 += 64) {
#pragma unroll
    for (int it = 0; it < 4; ++it) {
      int rb = wave * 32 + it * 8;
      gld_lds16(A + (size_t)(bm + rb + rel8) * lda + k0 + csw, &As[rb * 64]);
    }
#pragma unroll
    for (int it = 0; it < 4; ++it) {
      int rb = wave * 32 + it * 8;
      int wr = bn + rb + rel8;
      if (wr >= N) wr = N - 1;
      gld_lds16(W + (size_t)wr * ldw + k0 + csw, &Ws[rb * 64]);
    }
    __syncthreads();
#pragma unroll
    for (int kk = 0; kk < 64; kk += 32) {
      s16x8 a[4], b[4];
#pragma unroll
      for (int mt = 0; mt < 4; ++mt)
        a[mt] = *(const s16x8*)&As[(wm + mt * 16 + ln) * 64 + ((kk / 8 + quad) ^ (ln & 7)) * 8];
#pragma unroll
      for (int nt = 0; nt < 4; ++nt)
        b[nt] = *(const s16x8*)&Ws[(wn + nt * 16 + ln) * 64 + ((kk / 8 + quad) ^ (ln & 7)) * 8];
#pragma unroll
      for (int mt = 0; mt < 4; ++mt)
#pragma unroll
        for (int nt = 0; nt < 4; ++nt)
          acc[mt][nt] = __builtin_amdgcn_mfma_f32_16x16x32_bf16(a[mt], b[nt], acc[mt][nt], 0, 0, 0);
    }
    __syncthreads();
  }
#pragma unroll
  for (int mt = 0; mt < 4; ++mt) {
    int row = bm + wm + mt * 16 + quad * 4;
#pragma unroll
    for (int nt = 0; nt < 4; ++nt) {
      int col = bn + wn + nt * 16 + ln;
      if (col < N) {
#pragma unroll
        for (int r = 0; r < 4; ++r) {
          float v = acc[mt][nt][r];
          if (OUT_F32)
            ((float*)C)[(size_t)(row + r) * N + col] = v;
          else
            ((unsigned short*)C)[(size_t)(row + r) * N + col] = f2bf(v);
        }
      }
    }
  }
}

// ---------------- q GEMM v1 (restored): fused RoPE + log2e + permuted store --
__global__ __launch_bounds__(256, 2) void gemm_q_rope(
    const unsigned short* __restrict__ A, int lda,
    const unsigned short* __restrict__ W, int ldw,
    unsigned short* __restrict__ Qry, int K)
{
  __shared__ __align__(16) unsigned short As[128 * 64];
  __shared__ __align__(16) unsigned short Ws[128 * 64];
  const int tid = threadIdx.x;
  const int wave = tid >> 6;
  const int lane = tid & 63;
  const int ln = lane & 15;
  const int quad = lane >> 4;
  const int bm = blockIdx.y * 128;
  const int bn = blockIdx.x * 128;
  const int wm = (wave >> 1) * 64;
  const int wn = (wave & 1) * 64;

  f32x4 acc[4][4] = {};
  const int rel8 = lane >> 3;
  const int csw = ((lane & 7) ^ rel8) * 8;

  for (int k0 = 0; k0 < K; k0 += 64) {
#pragma unroll
    for (int it = 0; it < 4; ++it) {
      int rb = wave * 32 + it * 8;
      gld_lds16(A + (size_t)(bm + rb + rel8) * lda + k0 + csw, &As[rb * 64]);
    }
#pragma unroll
    for (int it = 0; it < 4; ++it) {
      int rb = wave * 32 + it * 8;
      gld_lds16(W + (size_t)(bn + rb + rel8) * ldw + k0 + csw, &Ws[rb * 64]);
    }
    __syncthreads();
#pragma unroll
    for (int kk = 0; kk < 64; kk += 32) {
      s16x8 a[4], b[4];
#pragma unroll
      for (int mt = 0; mt < 4; ++mt)
        a[mt] = *(const s16x8*)&As[(wm + mt * 16 + ln) * 64 + ((kk / 8 + quad) ^ (ln & 7)) * 8];
#pragma unroll
      for (int nt = 0; nt < 4; ++nt)
        b[nt] = *(const s16x8*)&Ws[(wn + nt * 16 + ln) * 64 + ((kk / 8 + quad) ^ (ln & 7)) * 8];
#pragma unroll
      for (int mt = 0; mt < 4; ++mt)
#pragma unroll
        for (int nt = 0; nt < 4; ++nt)
          acc[mt][nt] = __builtin_amdgcn_mfma_f32_16x16x32_bf16(a[mt], b[nt], acc[mt][nt], 0, 0, 0);
    }
    __syncthreads();
  }
  const bool odd = (ln & 1);
#pragma unroll
  for (int mt = 0; mt < 4; ++mt) {
    int rowb = bm + wm + mt * 16 + quad * 4;
#pragma unroll
    for (int nt = 0; nt < 4; ++nt) {
      int col = bn + wn + nt * 16 + ln;
      int h = col >> 7, d = col & 127;
#pragma unroll
      for (int r = 0; r < 4; ++r) {
        float v = acc[mt][nt][r];
        float other = __shfl_xor(v, 1);
        int row = rowb + r;
        int b = row >> 11, s = row & 2047;
        float y = v;
        if (d >= NOPED) {
          int i = (d - NOPED) >> 1;
          float theta = exp2f(-(float)i * (13.287712379549449f / 32.f));
          float ang = (float)s * theta;
          float sn, c;
          sincosf(ang, &sn, &c);
          y = v * c + (odd ? other * sn : -other * sn);
        }
        y *= LOG2E;   // fold softmax exp->exp2 conversion into Q
        Qry[((size_t)(b * NH + h) * SEQ + s) * QKD + d] = f2bf(y);
      }
    }
  }
}

// ---------------- fused prep: Key (nope + RoPE) AND V^T, one KVB pass --------
__global__ void prep_kv(const unsigned short* __restrict__ kvb,
                        const unsigned short* __restrict__ cqkv,
                        unsigned short* __restrict__ Key,
                        unsigned short* __restrict__ VT) {
  __shared__ unsigned short vt[64][132];
  __shared__ unsigned short kr[64][64];
  int blk = blockIdx.x;
  int bh = blk >> 5, st = blk & 31;
  int b = bh >> 4, h = bh & 15;
  int s0 = st * 64;
  int tid = threadIdx.x;

  // krot: 64 rows x 32 pairs
  for (int idx = tid; idx < 64 * 32; idx += 256) {
    int sl = idx >> 5, i = idx & 31;
    int s = s0 + sl;
    const unsigned short* rp = cqkv + (size_t)(b * SEQ + s) * NCOMB + QRANK + KVRANK;
    float x0 = bf2f(rp[2 * i]);
    float x1 = bf2f(rp[2 * i + 1]);
    float theta = exp2f(-(float)i * (13.287712379549449f / 32.f));
    float ang = (float)s * theta;
    float sn, c;
    sincosf(ang, &sn, &c);
    kr[sl][2 * i] = f2bf(x0 * c - x1 * sn);
    kr[sl][2 * i + 1] = f2bf(x1 * c + x0 * sn);
  }
  // V tile load (16B vectors)
  for (int idx = tid; idx < 64 * 16; idx += 256) {
    int sl = idx >> 4, dc = idx & 15;
    s16x8 v = *(const s16x8*)(kvb + (size_t)(b * SEQ + s0 + sl) * (NH * 192) + h * 192 + NOPED + dc * 8);
    *(s16x8*)&vt[sl][dc * 8] = v;
  }
  __syncthreads();
  // Key write: d<64 nope straight from kvb, d>=64 from kr
  for (int idx = tid; idx < 64 * 128; idx += 256) {
    int sl = idx >> 7, d = idx & 127;
    unsigned short v;
    if (d < NOPED)
      v = kvb[(size_t)(b * SEQ + s0 + sl) * (NH * 192) + h * 192 + d];
    else
      v = kr[sl][d - NOPED];
    Key[((size_t)bh * SEQ + s0 + sl) * QKD + d] = v;
  }
  // V^T write
  for (int idx = tid; idx < 64 * 128; idx += 256) {
    int d = idx >> 6, sl = idx & 63;
    VT[((size_t)bh * VD + d) * SEQ + s0 + sl] = vt[sl][d];
  }
}

// ---------------- flash attention v12: QBLK=256, 8 waves — halve staged bytes
// R6 analysis: flash stages 512 blocks x 32 tiles x 32KB = 512MB through
// L2/L3 into LDS = 6.6 TB/s over 77us — at the fabric service ceiling (K/V
// footprint >> 4MB/XCD so largely L3-served). MfmaUtil(37)+VALUBusy(43) are
// capped by this flow, not latency (loads prefetched a full tile ahead).
// v12: 256 Q-rows per block (8 waves x 32 rows, 512 threads, grid 32x8=256
// blocks) -> K/V staged once per 256 Q-rows = 256MB total. Per-wave state
// (qa/sc/o/l_i) and the v10 cross-tile ping-pong structure are UNCHANGED;
// only the stage loops halve (it<2). LDS 80KB; default dispatch groups
// bh%8 per XCD (4bh x 1MB K/V = 4MB = L2/XCD) so no swizzle needed.
__global__ __launch_bounds__(512, 2) void flash_attn(
    const unsigned short* __restrict__ Q,
    const unsigned short* __restrict__ Kt,     // (BHD, SEQ, 128)
    const unsigned short* __restrict__ VT,     // (BHD, 128, SEQ)
    unsigned short* __restrict__ O)
{
  __shared__ __align__(16) unsigned short Ks[2][64 * 128];
  __shared__ __align__(16) unsigned short Vs[3][128 * 64];

  const int tid = threadIdx.x;
  const int wave = tid >> 6;           // 0..7
  const int lane = tid & 63;
  const int ln = lane & 15;
  const int quad = lane >> 4;
  const int bh = blockIdx.x;
  const int q0 = blockIdx.y * 256;
  const int b = bh >> 4, h = bh & 15;

  // ---- Q fragments straight from global (B-operand of S^T = K·Q^T)
  s16x8 qa[2][4];
#pragma unroll
  for (int mt = 0; mt < 2; ++mt) {
    const unsigned short* qrow = Q + ((size_t)bh * SEQ + q0 + wave * 32 + mt * 16 + ln) * QKD;
#pragma unroll
    for (int kx = 0; kx < 4; ++kx)
      qa[mt][kx] = *(const s16x8*)(qrow + kx * 32 + quad * 8);
  }

  const int krel = lane >> 4, kcch = lane & 15;
  const int vrel8 = lane >> 3;
  const int vc8 = (lane & 7) ^ vrel8;

  // 4 async loads per wave per tile (2 K + 2 V); tile t -> Ks[t&1], Vs[t%3]
  auto stage = [&](unsigned short* Kd, unsigned short* Vd, int kt) {
#pragma unroll
    for (int it = 0; it < 2; ++it) {
      int rb = wave * 8 + it * 4;
      int rr = rb + krel;
      int c = kcch ^ (rr & 15);
      gld_lds16(Kt + ((size_t)bh * SEQ + kt * 64 + rr) * QKD + c * 8, Kd + rb * 128);
    }
#pragma unroll
    for (int it = 0; it < 2; ++it) {
      int rb = wave * 16 + it * 8;
      gld_lds16(VT + ((size_t)bh * VD + rb + vrel8) * SEQ + kt * 64 + vc8 * 8, Vd + rb * 64);
    }
  };

  f32x4 o[2][8] = {};              // o[mt][dt]: d = dt*16+quad*4+r, q = mt*16+ln
  float l_i[2] = {0.f, 0.f};

  // ---- chunk helpers (all inlined; call sites use literal args)
  auto sc_init = [&](f32x4 (&sc)[2][4]) {
#pragma unroll
    for (int mt = 0; mt < 2; ++mt)
#pragma unroll
      for (int t = 0; t < 4; ++t)
        sc[mt][t] = (f32x4){-20.f, -20.f, -20.f, -20.f};
  };
  auto qk_kx = [&](int kx, const unsigned short* Kc, f32x4 (&sc)[2][4]) {
    s16x8 ak[4];
#pragma unroll
    for (int t = 0; t < 4; ++t)
      ak[t] = *(const s16x8*)&Kc[(t * 16 + ln) * 128 + ((kx * 4 + quad) ^ ln) * 8];
#pragma unroll
    for (int mt = 0; mt < 2; ++mt)
#pragma unroll
      for (int t = 0; t < 4; ++t)
        sc[mt][t] = __builtin_amdgcn_mfma_f32_16x16x32_bf16(ak[t], qa[mt][kx], sc[mt][t], 0, 0, 0);
  };
  auto sm_mt = [&](int mt, f32x4 (&sc)[2][4], s16x8 (&pfrag)[2][2]) {
    float rs = 0.f;
    unsigned int pw[4][2];
#pragma unroll
    for (int t = 0; t < 4; ++t) {
      float e0 = vexp2(sc[mt][t][0]);
      float e1 = vexp2(sc[mt][t][1]);
      float e2 = vexp2(sc[mt][t][2]);
      float e3 = vexp2(sc[mt][t][3]);
      unsigned int p01 = pk_bf16_trunc(e0, e1);
      unsigned int p23 = pk_bf16_trunc(e2, e3);
      pw[t][0] = p01; pw[t][1] = p23;
      rs += (__uint_as_float(p01 << 16) + __uint_as_float(p01 & 0xffff0000u))
          + (__uint_as_float(p23 << 16) + __uint_as_float(p23 & 0xffff0000u));
    }
    rs += __shfl_xor(rs, 16);
    rs += __shfl_xor(rs, 32);
    l_i[mt] += rs;
#pragma unroll
    for (int W = 0; W < 2; ++W) {
      unsigned int u0 = pw[2 * W][0], v0 = pw[2 * W + 1][0];
      unsigned int u1 = pw[2 * W][1], v1 = pw[2 * W + 1][1];
      pl32swap(u0, v0); pl16swap(u0, v0);
      pl32swap(u1, v1); pl16swap(u1, v1);
      union { unsigned int u[4]; s16x8 v; } fb;
      fb.u[0] = u0;    // k_local = quad*8 + {0,1}
      fb.u[1] = u1;    // k_local = quad*8 + {2,3}
      fb.u[2] = v0;    // k_local = quad*8 + {4,5}
      fb.u[3] = v1;    // k_local = quad*8 + {6,7}
      pfrag[mt][W] = fb.v;
    }
  };
  auto pv_half = [&](int half, const unsigned short* Vc, s16x8 (&pfrag)[2][2]) {
#pragma unroll
    for (int dd = 0; dd < 4; ++dd) {
      int dt = half * 4 + dd;
      s16x8 av0 = *(const s16x8*)&Vc[(dt * 16 + ln) * 64 + ((quad ^ (ln & 7)) * 8)];
      s16x8 av1 = *(const s16x8*)&Vc[(dt * 16 + ln) * 64 + (((4 + quad) ^ (ln & 7)) * 8)];
#pragma unroll
      for (int mt = 0; mt < 2; ++mt) {
        o[mt][dt] = __builtin_amdgcn_mfma_f32_16x16x32_bf16(av0, pfrag[mt][0], o[mt][dt], 0, 0, 0);
        o[mt][dt] = __builtin_amdgcn_mfma_f32_16x16x32_bf16(av1, pfrag[mt][1], o[mt][dt], 0, 0, 0);
      }
    }
  };

  // ---- pipelined iteration: QK(kt)->scC interleaved with softmax+PV(kt-1)
  auto iter = [&](int kt, f32x4 (&scP)[2][4], f32x4 (&scC)[2][4]) {
    asm volatile("s_waitcnt vmcnt(0)" ::: "memory");     // tile kt staged
    asm volatile("s_barrier" ::: "memory");              // all reads of (kt+1)-buffers done
    if (kt + 1 < NT)
      stage(Ks[(kt + 1) & 1], Vs[(kt + 1) % 3], kt + 1);
    const unsigned short* Kc = Ks[kt & 1];
    const unsigned short* Vp = Vs[(kt - 1) % 3];
    s16x8 pfrag[2][2];
    __builtin_amdgcn_s_setprio(1);
    sc_init(scC);
    qk_kx(0, Kc, scC);
    sm_mt(0, scP, pfrag);
    qk_kx(1, Kc, scC);
    sm_mt(1, scP, pfrag);
    qk_kx(2, Kc, scC);
    pv_half(0, Vp, pfrag);
    qk_kx(3, Kc, scC);
    pv_half(1, Vp, pfrag);
    __builtin_amdgcn_s_setprio(0);
  };

  f32x4 scA[2][4], scB[2][4];

  // prologue: stage tiles 0 and 1; QK(0) -> scA
  stage(Ks[0], Vs[0], 0);
  asm volatile("s_waitcnt vmcnt(0)" ::: "memory");
  asm volatile("s_barrier" ::: "memory");
  stage(Ks[1], Vs[1], 1);
  __builtin_amdgcn_s_setprio(1);
  sc_init(scA);
  qk_kx(0, Ks[0], scA);
  qk_kx(1, Ks[0], scA);
  qk_kx(2, Ks[0], scA);
  qk_kx(3, Ks[0], scA);
  __builtin_amdgcn_s_setprio(0);

  // 15 pairs cover kt = 1..30 with static sc ping-pong
  int kt = 1;
#pragma unroll 1
  for (int p = 0; p < 15; ++p, kt += 2) {
    iter(kt, scA, scB);
    iter(kt + 1, scB, scA);
  }
  iter(31, scA, scB);

  // epilogue: softmax+PV for tile 31 (V in Vs[31 % 3] = Vs[1])
  {
    s16x8 pfrag[2][2];
    sm_mt(0, scB, pfrag);
    sm_mt(1, scB, pfrag);
    pv_half(0, Vs[1], pfrag);
    pv_half(1, Vs[1], pfrag);
  }

#pragma unroll
  for (int mt = 0; mt < 2; ++mt) {
    float inv = 1.f / l_i[mt];
    int s = q0 + wave * 32 + mt * 16 + ln;
    size_t rowbase = ((size_t)b * SEQ + s) * (NH * VD) + h * VD;
#pragma unroll
    for (int dt = 0; dt < 8; ++dt) {
      ushort4 pk;
      pk.x = f2bf(o[mt][dt][0] * inv);
      pk.y = f2bf(o[mt][dt][1] * inv);
      pk.z = f2bf(o[mt][dt][2] * inv);
      pk.w = f2bf(o[mt][dt][3] * inv);
      *(ushort4*)&O[rowbase + dt * 16 + quad * 4] = pk;
    }
  }
}

extern "C" void kernel_launch(void* const* d_in, const int* in_sizes, int n_in,
                              void* d_out, int out_size, void* d_ws, size_t ws_size,
                              hipStream_t stream) {
  const float* x_f    = (const float*)d_in[0];
  const float* qaw_f  = (const float*)d_in[1];
  const float* qbw_f  = (const float*)d_in[2];
  const float* kvaw_f = (const float*)d_in[3];
  const float* kvbw_f = (const float*)d_in[4];
  const float* ow_f   = (const float*)d_in[5];

  char* ws = (char*)d_ws;
  size_t off = 0;
  auto alloc = [&](size_t n) {
    unsigned short* p = (unsigned short*)(ws + off);
    off = (off + n * 2 + 255) & ~(size_t)255;
    return p;
  };
  unsigned short* Xb    = alloc((size_t)BS * EMB);
  unsigned short* Wcomb = alloc((size_t)NCOMB * EMB);
  unsigned short* Wqb   = alloc((size_t)(NH * QKD) * QRANK);
  unsigned short* Wkvb  = alloc((size_t)(NH * 192) * KVRANK);
  unsigned short* Wo    = alloc((size_t)EMB * (NH * VD));
  unsigned short* CQKV  = alloc((size_t)BS * NCOMB);
  unsigned short* KVB   = alloc((size_t)BS * (NH * 192));
  unsigned short* Qry   = alloc((size_t)BHD * SEQ * QKD);
  unsigned short* Key   = alloc((size_t)BHD * SEQ * QKD);
  unsigned short* Vt    = alloc((size_t)BHD * VD * SEQ);
  unsigned short* AO    = alloc((size_t)BS * (NH * VD));

  cast_all<<<dim3(8192), 256, 0, stream>>>(x_f, qaw_f, kvaw_f, qbw_f, kvbw_f, ow_f,
                                           Xb, Wcomb, Wqb, Wkvb, Wo);

  // [cq | ckv | rope(raw)] = x @ [q_a_w; kv_a_w]^T  (4096 x 2112, K=2048)
  gemm_bt<0><<<dim3((NCOMB + 127) / 128, BS / 128), 256, 0, stream>>>(
      Xb, EMB, Wcomb, EMB, CQKV, BS, NCOMB, EMB);
  // q = cq @ q_b_w^T, RoPE + log2e + permuted store (4096 x 2048, K=1536)
  gemm_q_rope<<<dim3((NH * QKD) / 128, BS / 128), 256, 0, stream>>>(
      CQKV, NCOMB, Wqb, QRANK, Qry, QRANK);
  // kvb = ckv @ kv_b_w^T (4096 x 3072, K=512)
  gemm_bt<0><<<dim3((NH * 192) / 128, BS / 128), 256, 0, stream>>>(
      CQKV + QRANK, NCOMB, Wkvb, KVRANK, KVB, BS, NH * 192, KVRANK);

  // fused Key + V^T prep (one KVB pass, one launch)
  prep_kv<<<dim3(BHD * (SEQ / 64)), 256, 0, stream>>>(KVB, CQKV, Key, Vt);

  // QBLK=256: 8 waves, grid (32, 8)
  flash_attn<<<dim3(BHD, SEQ / 256), 512, 0, stream>>>(Qry, Key, Vt, AO);

  // out = AO @ o_w^T (fp32 out)
  gemm_bt<1><<<dim3(EMB / 128, BS / 128), 256, 0, stream>>>(
      AO, NH * VD, Wo, NH * VD, d_out, BS, EMB, NH * VD);
}

// Round 8
// 353.996 us; speedup vs baseline: 1.1507x; 1.0586x over previous
//
#include <hip/hip_runtime.h>
#include <stdint.h>

#define EMB 2048
#define NH 16
#define QRANK 1536
#define KVRANK 512
#define ROPED 64
#define NOPED 64
#define VD 128
#define QKD 128
#define SEQ 2048
#define BATCH 2
#define BS 4096            // BATCH*SEQ
#define BHD 32             // BATCH*NH
#define NCOMB 2112         // QRANK + KVRANK + ROPED
#define LOG2E 1.4426950408889634f
#define NT (SEQ / 64)      // 32 KV tiles

typedef __attribute__((ext_vector_type(4))) float f32x4;
typedef __attribute__((ext_vector_type(8))) short s16x8;
typedef __attribute__((ext_vector_type(4))) short s16x4;
typedef __attribute__((ext_vector_type(2))) unsigned int u32x2;

__device__ __forceinline__ float bf2f(unsigned short u) {
  return __uint_as_float(((unsigned int)u) << 16);
}
__device__ __forceinline__ unsigned short f2bf(float f) {
  unsigned int u = __float_as_uint(f);
  u += 0x7fff + ((u >> 16) & 1);
  return (unsigned short)(u >> 16);
}

__device__ __forceinline__ float vexp2(float x) {
#if __has_builtin(__builtin_amdgcn_exp2f)
  return __builtin_amdgcn_exp2f(x);
#else
  return exp2f(x);
#endif
}

// pack hi16(e1):hi16(e0) into one dword (bf16 truncation)
__device__ __forceinline__ unsigned int pk_bf16_trunc(float e0, float e1) {
#if __has_builtin(__builtin_amdgcn_perm)
  return __builtin_amdgcn_perm(__float_as_uint(e1), __float_as_uint(e0), 0x07060302u);
#else
  return (__float_as_uint(e1) & 0xffff0000u) | (__float_as_uint(e0) >> 16);
#endif
}

// CDNA4 lane-row swaps (both outputs used).
__device__ __forceinline__ void pl32swap(unsigned int& a, unsigned int& b) {
#if __has_builtin(__builtin_amdgcn_permlane32_swap)
  u32x2 r = __builtin_amdgcn_permlane32_swap(a, b, false, false);
  a = r.x; b = r.y;
#else
  asm("v_permlane32_swap_b32 %0, %1" : "+v"(a), "+v"(b));
#endif
}
__device__ __forceinline__ void pl16swap(unsigned int& a, unsigned int& b) {
#if __has_builtin(__builtin_amdgcn_permlane16_swap)
  u32x2 r = __builtin_amdgcn_permlane16_swap(a, b, false, false);
  a = r.x; b = r.y;
#else
  asm("v_permlane16_swap_b32 %0, %1" : "+v"(a), "+v"(b));
#endif
}

__device__ __forceinline__ void gld_lds16(const unsigned short* g, unsigned short* l) {
  __builtin_amdgcn_global_load_lds((const __attribute__((address_space(1))) void*)g,
                                   (__attribute__((address_space(3))) void*)l,
                                   16, 0, 0);
}

// ---------------- fused cast f32 -> bf16, all 6 tensors, one launch ----------
#define N4_X   (BS * EMB / 4)
#define N4_QA  (QRANK * EMB / 4)
#define N4_KVA ((KVRANK + ROPED) * EMB / 4)
#define N4_QB  (NH * QKD * QRANK / 4)
#define N4_KVB (NH * 192 * KVRANK / 4)
#define N4_O   (EMB * NH * VD / 4)
#define N4_TOT (N4_X + N4_QA + N4_KVA + N4_QB + N4_KVB + N4_O)

__global__ void cast_all(const float* __restrict__ x, const float* __restrict__ qa,
                         const float* __restrict__ kva, const float* __restrict__ qb,
                         const float* __restrict__ kvb, const float* __restrict__ ow,
                         unsigned short* __restrict__ Xb, unsigned short* __restrict__ Wcomb,
                         unsigned short* __restrict__ Wqb, unsigned short* __restrict__ Wkvb,
                         unsigned short* __restrict__ Wo) {
  int i = blockIdx.x * blockDim.x + threadIdx.x;
  int stride = gridDim.x * blockDim.x;
  for (; i < N4_TOT; i += stride) {
    const float4* src;
    ushort4* dst;
    int j = i;
    if (j < N4_X) { src = (const float4*)x; dst = (ushort4*)Xb; }
    else if ((j -= N4_X) < N4_QA) { src = (const float4*)qa; dst = (ushort4*)Wcomb; }
    else if ((j -= N4_QA) < N4_KVA) { src = (const float4*)kva; dst = (ushort4*)(Wcomb + (size_t)QRANK * EMB); }
    else if ((j -= N4_KVA) < N4_QB) { src = (const float4*)qb; dst = (ushort4*)Wqb; }
    else if ((j -= N4_QB) < N4_KVB) { src = (const float4*)kvb; dst = (ushort4*)Wkvb; }
    else { j -= N4_KVB; src = (const float4*)ow; dst = (ushort4*)Wo; }
    float4 v = src[j];
    ushort4 o;
    o.x = f2bf(v.x); o.y = f2bf(v.y); o.z = f2bf(v.z); o.w = f2bf(v.w);
    dst[j] = o;
  }
}

// ---------------- GEMM v3: v1 schedule + 3-blocks/CU + XCD-bijective swizzle -
// C[M,N] = A[M,K(lda)] * W[N,K(ldw)]^T. 128x128 tile, BK=64, 4 waves 2x2.
// R7 budget math: GEMM aggregate ~255us = ~425 TF, vs the identical
// m97-structure's 874-912 TF. Difference: m97 ran ~3 blocks/CU (VGPR 164);
// ours was pinned to 2 by __launch_bounds__(256,2) + grids of 512-768 blocks.
// v3: (256,3) for 12 waves/CU (LDS 96KB fits), and a flat 1D grid with the
// bijective XCD swizzle (all grids %8==0) so consecutive tiles share panels
// within one XCD's L2 instead of striping across 8 L2s (T1).
template <int OUT_F32>
__global__ __launch_bounds__(256, 3) void gemm_bt(
    const unsigned short* __restrict__ A, int lda,
    const unsigned short* __restrict__ W, int ldw,
    void* __restrict__ C, int M, int N, int K)
{
  __shared__ __align__(16) unsigned short As[128 * 64];
  __shared__ __align__(16) unsigned short Ws[128 * 64];
  const int tid = threadIdx.x;
  const int wave = tid >> 6;
  const int lane = tid & 63;
  const int ln = lane & 15;
  const int quad = lane >> 4;
  // XCD-bijective swizzle (requires gridDim.x % 8 == 0, guaranteed by launcher)
  const int nwg = gridDim.x;
  const int cpx = nwg >> 3;
  const int swz = (blockIdx.x & 7) * cpx + (blockIdx.x >> 3);
  const int nbx = (N + 127) >> 7;
  const int bm = (swz / nbx) * 128;
  const int bn = (swz % nbx) * 128;
  const int wm = (wave >> 1) * 64;
  const int wn = (wave & 1) * 64;

  f32x4 acc[4][4] = {};

  const int rel8 = lane >> 3;
  const int csw = ((lane & 7) ^ rel8) * 8;

  for (int k0 = 0; k0 < K; k0 += 64) {
#pragma unroll
    for (int it = 0; it < 4; ++it) {
      int rb = wave * 32 + it * 8;
      gld_lds16(A + (size_t)(bm + rb + rel8) * lda + k0 + csw, &As[rb * 64]);
    }
#pragma unroll
    for (int it = 0; it < 4; ++it) {
      int rb = wave * 32 + it * 8;
      int wr = bn + rb + rel8;
      if (wr >= N) wr = N - 1;
      gld_lds16(W + (size_t)wr * ldw + k0 + csw, &Ws[rb * 64]);
    }
    __syncthreads();
#pragma unroll
    for (int kk = 0; kk < 64; kk += 32) {
      s16x8 a[4], b[4];
#pragma unroll
      for (int mt = 0; mt < 4; ++mt)
        a[mt] = *(const s16x8*)&As[(wm + mt * 16 + ln) * 64 + ((kk / 8 + quad) ^ (ln & 7)) * 8];
#pragma unroll
      for (int nt = 0; nt < 4; ++nt)
        b[nt] = *(const s16x8*)&Ws[(wn + nt * 16 + ln) * 64 + ((kk / 8 + quad) ^ (ln & 7)) * 8];
#pragma unroll
      for (int mt = 0; mt < 4; ++mt)
#pragma unroll
        for (int nt = 0; nt < 4; ++nt)
          acc[mt][nt] = __builtin_amdgcn_mfma_f32_16x16x32_bf16(a[mt], b[nt], acc[mt][nt], 0, 0, 0);
    }
    __syncthreads();
  }
#pragma unroll
  for (int mt = 0; mt < 4; ++mt) {
    int row = bm + wm + mt * 16 + quad * 4;
#pragma unroll
    for (int nt = 0; nt < 4; ++nt) {
      int col = bn + wn + nt * 16 + ln;
      if (col < N) {
#pragma unroll
        for (int r = 0; r < 4; ++r) {
          float v = acc[mt][nt][r];
          if (OUT_F32)
            ((float*)C)[(size_t)(row + r) * N + col] = v;
          else
            ((unsigned short*)C)[(size_t)(row + r) * N + col] = f2bf(v);
        }
      }
    }
  }
}

// ---------------- q GEMM v3: same occupancy+swizzle, fused RoPE epilogue -----
__global__ __launch_bounds__(256, 3) void gemm_q_rope(
    const unsigned short* __restrict__ A, int lda,
    const unsigned short* __restrict__ W, int ldw,
    unsigned short* __restrict__ Qry, int K)
{
  __shared__ __align__(16) unsigned short As[128 * 64];
  __shared__ __align__(16) unsigned short Ws[128 * 64];
  const int tid = threadIdx.x;
  const int wave = tid >> 6;
  const int lane = tid & 63;
  const int ln = lane & 15;
  const int quad = lane >> 4;
  const int nwg = gridDim.x;
  const int cpx = nwg >> 3;
  const int swz = (blockIdx.x & 7) * cpx + (blockIdx.x >> 3);
  const int nbx = (NH * QKD) >> 7;           // 16
  const int bm = (swz / nbx) * 128;
  const int bn = (swz % nbx) * 128;
  const int wm = (wave >> 1) * 64;
  const int wn = (wave & 1) * 64;

  f32x4 acc[4][4] = {};
  const int rel8 = lane >> 3;
  const int csw = ((lane & 7) ^ rel8) * 8;

  for (int k0 = 0; k0 < K; k0 += 64) {
#pragma unroll
    for (int it = 0; it < 4; ++it) {
      int rb = wave * 32 + it * 8;
      gld_lds16(A + (size_t)(bm + rb + rel8) * lda + k0 + csw, &As[rb * 64]);
    }
#pragma unroll
    for (int it = 0; it < 4; ++it) {
      int rb = wave * 32 + it * 8;
      gld_lds16(W + (size_t)(bn + rb + rel8) * ldw + k0 + csw, &Ws[rb * 64]);
    }
    __syncthreads();
#pragma unroll
    for (int kk = 0; kk < 64; kk += 32) {
      s16x8 a[4], b[4];
#pragma unroll
      for (int mt = 0; mt < 4; ++mt)
        a[mt] = *(const s16x8*)&As[(wm + mt * 16 + ln) * 64 + ((kk / 8 + quad) ^ (ln & 7)) * 8];
#pragma unroll
      for (int nt = 0; nt < 4; ++nt)
        b[nt] = *(const s16x8*)&Ws[(wn + nt * 16 + ln) * 64 + ((kk / 8 + quad) ^ (ln & 7)) * 8];
#pragma unroll
      for (int mt = 0; mt < 4; ++mt)
#pragma unroll
        for (int nt = 0; nt < 4; ++nt)
          acc[mt][nt] = __builtin_amdgcn_mfma_f32_16x16x32_bf16(a[mt], b[nt], acc[mt][nt], 0, 0, 0);
    }
    __syncthreads();
  }
  const bool odd = (ln & 1);
#pragma unroll
  for (int mt = 0; mt < 4; ++mt) {
    int rowb = bm + wm + mt * 16 + quad * 4;
#pragma unroll
    for (int nt = 0; nt < 4; ++nt) {
      int col = bn + wn + nt * 16 + ln;
      int h = col >> 7, d = col & 127;
#pragma unroll
      for (int r = 0; r < 4; ++r) {
        float v = acc[mt][nt][r];
        float other = __shfl_xor(v, 1);
        int row = rowb + r;
        int b = row >> 11, s = row & 2047;
        float y = v;
        if (d >= NOPED) {
          int i = (d - NOPED) >> 1;
          float theta = exp2f(-(float)i * (13.287712379549449f / 32.f));
          float ang = (float)s * theta;
          float sn, c;
          sincosf(ang, &sn, &c);
          y = v * c + (odd ? other * sn : -other * sn);
        }
        y *= LOG2E;   // fold softmax exp->exp2 conversion into Q
        Qry[((size_t)(b * NH + h) * SEQ + s) * QKD + d] = f2bf(y);
      }
    }
  }
}

// ---------------- fused prep: Key (nope + RoPE) AND V^T, one KVB pass --------
__global__ void prep_kv(const unsigned short* __restrict__ kvb,
                        const unsigned short* __restrict__ cqkv,
                        unsigned short* __restrict__ Key,
                        unsigned short* __restrict__ VT) {
  __shared__ unsigned short vt[64][132];
  __shared__ unsigned short kr[64][64];
  int blk = blockIdx.x;
  int bh = blk >> 5, st = blk & 31;
  int b = bh >> 4, h = bh & 15;
  int s0 = st * 64;
  int tid = threadIdx.x;

  // krot: 64 rows x 32 pairs
  for (int idx = tid; idx < 64 * 32; idx += 256) {
    int sl = idx >> 5, i = idx & 31;
    int s = s0 + sl;
    const unsigned short* rp = cqkv + (size_t)(b * SEQ + s) * NCOMB + QRANK + KVRANK;
    float x0 = bf2f(rp[2 * i]);
    float x1 = bf2f(rp[2 * i + 1]);
    float theta = exp2f(-(float)i * (13.287712379549449f / 32.f));
    float ang = (float)s * theta;
    float sn, c;
    sincosf(ang, &sn, &c);
    kr[sl][2 * i] = f2bf(x0 * c - x1 * sn);
    kr[sl][2 * i + 1] = f2bf(x1 * c + x0 * sn);
  }
  // V tile load (16B vectors)
  for (int idx = tid; idx < 64 * 16; idx += 256) {
    int sl = idx >> 4, dc = idx & 15;
    s16x8 v = *(const s16x8*)(kvb + (size_t)(b * SEQ + s0 + sl) * (NH * 192) + h * 192 + NOPED + dc * 8);
    *(s16x8*)&vt[sl][dc * 8] = v;
  }
  __syncthreads();
  // Key write: d<64 nope straight from kvb, d>=64 from kr
  for (int idx = tid; idx < 64 * 128; idx += 256) {
    int sl = idx >> 7, d = idx & 127;
    unsigned short v;
    if (d < NOPED)
      v = kvb[(size_t)(b * SEQ + s0 + sl) * (NH * 192) + h * 192 + d];
    else
      v = kr[sl][d - NOPED];
    Key[((size_t)bh * SEQ + s0 + sl) * QKD + d] = v;
  }
  // V^T write
  for (int idx = tid; idx < 64 * 128; idx += 256) {
    int d = idx >> 6, sl = idx & 63;
    VT[((size_t)bh * VD + d) * SEQ + s0 + sl] = vt[sl][d];
  }
}

// ---------------- flash attention v10 (reverted, final): cross-tile pipeline -
// Flash probe history: v9 conflicts-fix 93.6->88; v10 pipeline 88->86.6 (77.4
// in r6 rerun — band is wide); v11 3-blk/48KB 114.7 (REGRESS: grid=2/CU);
// v12 QBLK=256 84.8 (REGRESS: 1 blk/CU lockstep). v10 = measured best.
// Decomposition: per-CU LDS floor (8192 b128 reads x ~12cy ~= 41us + staging
// ~7us) vs MFMA floor 27.5us -> ~77us is near-floor. Flash tuning closed.
__global__ __launch_bounds__(256, 2) void flash_attn(
    const unsigned short* __restrict__ Q,
    const unsigned short* __restrict__ Kt,     // (BHD, SEQ, 128)
    const unsigned short* __restrict__ VT,     // (BHD, 128, SEQ)
    unsigned short* __restrict__ O)
{
  __shared__ __align__(16) unsigned short Ks[2][64 * 128];
  __shared__ __align__(16) unsigned short Vs[3][128 * 64];

  const int tid = threadIdx.x;
  const int wave = tid >> 6;
  const int lane = tid & 63;
  const int ln = lane & 15;
  const int quad = lane >> 4;
  const int bh = blockIdx.x;
  const int q0 = blockIdx.y * 128;
  const int b = bh >> 4, h = bh & 15;

  // ---- Q fragments straight from global (B-operand of S^T = K·Q^T)
  s16x8 qa[2][4];
#pragma unroll
  for (int mt = 0; mt < 2; ++mt) {
    const unsigned short* qrow = Q + ((size_t)bh * SEQ + q0 + wave * 32 + mt * 16 + ln) * QKD;
#pragma unroll
    for (int kx = 0; kx < 4; ++kx)
      qa[mt][kx] = *(const s16x8*)(qrow + kx * 32 + quad * 8);
  }

  const int krel = lane >> 4, kcch = lane & 15;
  const int vrel8 = lane >> 3;
  const int vc8 = (lane & 7) ^ vrel8;

  // 8 async loads per wave per tile (4 K + 4 V); tile t -> Ks[t&1], Vs[t%3]
  auto stage = [&](unsigned short* Kd, unsigned short* Vd, int kt) {
#pragma unroll
    for (int it = 0; it < 4; ++it) {
      int rb = wave * 16 + it * 4;
      int rr = rb + krel;
      int c = kcch ^ (rr & 15);
      gld_lds16(Kt + ((size_t)bh * SEQ + kt * 64 + rr) * QKD + c * 8, Kd + rb * 128);
    }
#pragma unroll
    for (int it = 0; it < 4; ++it) {
      int rb = wave * 32 + it * 8;
      gld_lds16(VT + ((size_t)bh * VD + rb + vrel8) * SEQ + kt * 64 + vc8 * 8, Vd + rb * 64);
    }
  };

  f32x4 o[2][8] = {};              // o[mt][dt]: d = dt*16+quad*4+r, q = mt*16+ln
  float l_i[2] = {0.f, 0.f};

  // ---- chunk helpers (all inlined; call sites use literal args)
  auto sc_init = [&](f32x4 (&sc)[2][4]) {
#pragma unroll
    for (int mt = 0; mt < 2; ++mt)
#pragma unroll
      for (int t = 0; t < 4; ++t)
        sc[mt][t] = (f32x4){-20.f, -20.f, -20.f, -20.f};
  };
  auto qk_kx = [&](int kx, const unsigned short* Kc, f32x4 (&sc)[2][4]) {
    s16x8 ak[4];
#pragma unroll
    for (int t = 0; t < 4; ++t)
      ak[t] = *(const s16x8*)&Kc[(t * 16 + ln) * 128 + ((kx * 4 + quad) ^ ln) * 8];
#pragma unroll
    for (int mt = 0; mt < 2; ++mt)
#pragma unroll
      for (int t = 0; t < 4; ++t)
        sc[mt][t] = __builtin_amdgcn_mfma_f32_16x16x32_bf16(ak[t], qa[mt][kx], sc[mt][t], 0, 0, 0);
  };
  auto sm_mt = [&](int mt, f32x4 (&sc)[2][4], s16x8 (&pfrag)[2][2]) {
    float rs = 0.f;
    unsigned int pw[4][2];
#pragma unroll
    for (int t = 0; t < 4; ++t) {
      float e0 = vexp2(sc[mt][t][0]);
      float e1 = vexp2(sc[mt][t][1]);
      float e2 = vexp2(sc[mt][t][2]);
      float e3 = vexp2(sc[mt][t][3]);
      unsigned int p01 = pk_bf16_trunc(e0, e1);
      unsigned int p23 = pk_bf16_trunc(e2, e3);
      pw[t][0] = p01; pw[t][1] = p23;
      rs += (__uint_as_float(p01 << 16) + __uint_as_float(p01 & 0xffff0000u))
          + (__uint_as_float(p23 << 16) + __uint_as_float(p23 & 0xffff0000u));
    }
    rs += __shfl_xor(rs, 16);
    rs += __shfl_xor(rs, 32);
    l_i[mt] += rs;
#pragma unroll
    for (int W = 0; W < 2; ++W) {
      unsigned int u0 = pw[2 * W][0], v0 = pw[2 * W + 1][0];
      unsigned int u1 = pw[2 * W][1], v1 = pw[2 * W + 1][1];
      pl32swap(u0, v0); pl16swap(u0, v0);
      pl32swap(u1, v1); pl16swap(u1, v1);
      union { unsigned int u[4]; s16x8 v; } fb;
      fb.u[0] = u0;    // k_local = quad*8 + {0,1}
      fb.u[1] = u1;    // k_local = quad*8 + {2,3}
      fb.u[2] = v0;    // k_local = quad*8 + {4,5}
      fb.u[3] = v1;    // k_local = quad*8 + {6,7}
      pfrag[mt][W] = fb.v;
    }
  };
  auto pv_half = [&](int half, const unsigned short* Vc, s16x8 (&pfrag)[2][2]) {
#pragma unroll
    for (int dd = 0; dd < 4; ++dd) {
      int dt = half * 4 + dd;
      s16x8 av0 = *(const s16x8*)&Vc[(dt * 16 + ln) * 64 + ((quad ^ (ln & 7)) * 8)];
      s16x8 av1 = *(const s16x8*)&Vc[(dt * 16 + ln) * 64 + (((4 + quad) ^ (ln & 7)) * 8)];
#pragma unroll
      for (int mt = 0; mt < 2; ++mt) {
        o[mt][dt] = __builtin_amdgcn_mfma_f32_16x16x32_bf16(av0, pfrag[mt][0], o[mt][dt], 0, 0, 0);
        o[mt][dt] = __builtin_amdgcn_mfma_f32_16x16x32_bf16(av1, pfrag[mt][1], o[mt][dt], 0, 0, 0);
      }
    }
  };

  // ---- pipelined iteration: QK(kt)->scC interleaved with softmax+PV(kt-1)
  auto iter = [&](int kt, f32x4 (&scP)[2][4], f32x4 (&scC)[2][4]) {
    asm volatile("s_waitcnt vmcnt(0)" ::: "memory");     // tile kt staged
    asm volatile("s_barrier" ::: "memory");              // all reads of (kt+1)-buffers done
    if (kt + 1 < NT)
      stage(Ks[(kt + 1) & 1], Vs[(kt + 1) % 3], kt + 1);
    const unsigned short* Kc = Ks[kt & 1];
    const unsigned short* Vp = Vs[(kt - 1) % 3];
    s16x8 pfrag[2][2];
    __builtin_amdgcn_s_setprio(1);
    sc_init(scC);
    qk_kx(0, Kc, scC);
    sm_mt(0, scP, pfrag);
    qk_kx(1, Kc, scC);
    sm_mt(1, scP, pfrag);
    qk_kx(2, Kc, scC);
    pv_half(0, Vp, pfrag);
    qk_kx(3, Kc, scC);
    pv_half(1, Vp, pfrag);
    __builtin_amdgcn_s_setprio(0);
  };

  f32x4 scA[2][4], scB[2][4];

  // prologue: stage tiles 0 and 1; QK(0) -> scA
  stage(Ks[0], Vs[0], 0);
  asm volatile("s_waitcnt vmcnt(0)" ::: "memory");
  asm volatile("s_barrier" ::: "memory");
  stage(Ks[1], Vs[1], 1);
  __builtin_amdgcn_s_setprio(1);
  sc_init(scA);
  qk_kx(0, Ks[0], scA);
  qk_kx(1, Ks[0], scA);
  qk_kx(2, Ks[0], scA);
  qk_kx(3, Ks[0], scA);
  __builtin_amdgcn_s_setprio(0);

  // 15 pairs cover kt = 1..30 with static sc ping-pong
  int kt = 1;
#pragma unroll 1
  for (int p = 0; p < 15; ++p, kt += 2) {
    iter(kt, scA, scB);
    iter(kt + 1, scB, scA);
  }
  iter(31, scA, scB);

  // epilogue: softmax+PV for tile 31 (V in Vs[31 % 3] = Vs[1])
  {
    s16x8 pfrag[2][2];
    sm_mt(0, scB, pfrag);
    sm_mt(1, scB, pfrag);
    pv_half(0, Vs[1], pfrag);
    pv_half(1, Vs[1], pfrag);
  }

#pragma unroll
  for (int mt = 0; mt < 2; ++mt) {
    float inv = 1.f / l_i[mt];
    int s = q0 + wave * 32 + mt * 16 + ln;
    size_t rowbase = ((size_t)b * SEQ + s) * (NH * VD) + h * VD;
#pragma unroll
    for (int dt = 0; dt < 8; ++dt) {
      ushort4 pk;
      pk.x = f2bf(o[mt][dt][0] * inv);
      pk.y = f2bf(o[mt][dt][1] * inv);
      pk.z = f2bf(o[mt][dt][2] * inv);
      pk.w = f2bf(o[mt][dt][3] * inv);
      *(ushort4*)&O[rowbase + dt * 16 + quad * 4] = pk;
    }
  }
}

extern "C" void kernel_launch(void* const* d_in, const int* in_sizes, int n_in,
                              void* d_out, int out_size, void* d_ws, size_t ws_size,
                              hipStream_t stream) {
  const float* x_f    = (const float*)d_in[0];
  const float* qaw_f  = (const float*)d_in[1];
  const float* qbw_f  = (const float*)d_in[2];
  const float* kvaw_f = (const float*)d_in[3];
  const float* kvbw_f = (const float*)d_in[4];
  const float* ow_f   = (const float*)d_in[5];

  char* ws = (char*)d_ws;
  size_t off = 0;
  auto alloc = [&](size_t n) {
    unsigned short* p = (unsigned short*)(ws + off);
    off = (off + n * 2 + 255) & ~(size_t)255;
    return p;
  };
  unsigned short* Xb    = alloc((size_t)BS * EMB);
  unsigned short* Wcomb = alloc((size_t)NCOMB * EMB);
  unsigned short* Wqb   = alloc((size_t)(NH * QKD) * QRANK);
  unsigned short* Wkvb  = alloc((size_t)(NH * 192) * KVRANK);
  unsigned short* Wo    = alloc((size_t)EMB * (NH * VD));
  unsigned short* CQKV  = alloc((size_t)BS * NCOMB);
  unsigned short* KVB   = alloc((size_t)BS * (NH * 192));
  unsigned short* Qry   = alloc((size_t)BHD * SEQ * QKD);
  unsigned short* Key   = alloc((size_t)BHD * SEQ * QKD);
  unsigned short* Vt    = alloc((size_t)BHD * VD * SEQ);
  unsigned short* AO    = alloc((size_t)BS * (NH * VD));

  cast_all<<<dim3(8192), 256, 0, stream>>>(x_f, qaw_f, kvaw_f, qbw_f, kvbw_f, ow_f,
                                           Xb, Wcomb, Wqb, Wkvb, Wo);

  // [cq | ckv | rope(raw)] = x @ [q_a_w; kv_a_w]^T  (4096 x 2112, K=2048)
  // grid 17*32 = 544 blocks (544 % 8 == 0 for bijective XCD swizzle)
  gemm_bt<0><<<dim3(((NCOMB + 127) / 128) * (BS / 128)), 256, 0, stream>>>(
      Xb, EMB, Wcomb, EMB, CQKV, BS, NCOMB, EMB);
  // q = cq @ q_b_w^T, RoPE + log2e + permuted store; grid 16*32 = 512
  gemm_q_rope<<<dim3(((NH * QKD) / 128) * (BS / 128)), 256, 0, stream>>>(
      CQKV, NCOMB, Wqb, QRANK, Qry, QRANK);
  // kvb = ckv @ kv_b_w^T; grid 24*32 = 768
  gemm_bt<0><<<dim3(((NH * 192) / 128) * (BS / 128)), 256, 0, stream>>>(
      CQKV + QRANK, NCOMB, Wkvb, KVRANK, KVB, BS, NH * 192, KVRANK);

  // fused Key + V^T prep (one KVB pass, one launch)
  prep_kv<<<dim3(BHD * (SEQ / 64)), 256, 0, stream>>>(KVB, CQKV, Key, Vt);

  flash_attn<<<dim3(BHD, SEQ / 128), 256, 0, stream>>>(Qry, Key, Vt, AO);

  // out = AO @ o_w^T (fp32 out); grid 16*32 = 512
  gemm_bt<1><<<dim3((EMB / 128) * (BS / 128)), 256, 0, stream>>>(
      AO, NH * VD, Wo, NH * VD, d_out, BS, EMB, NH * VD);
}

// Round 9
// 332.838 us; speedup vs baseline: 1.2238x; 1.0636x over previous
//
#include <hip/hip_runtime.h>
#include <stdint.h>

#define EMB 2048
#define NH 16
#define QRANK 1536
#define KVRANK 512
#define ROPED 64
#define NOPED 64
#define VD 128
#define QKD 128
#define SEQ 2048
#define BATCH 2
#define BS 4096            // BATCH*SEQ
#define BHD 32             // BATCH*NH
#define NCOMB 2112         // QRANK + KVRANK + ROPED
#define LOG2E 1.4426950408889634f
#define NT (SEQ / 64)      // 32 KV tiles

typedef __attribute__((ext_vector_type(4))) float f32x4;
typedef __attribute__((ext_vector_type(8))) short s16x8;
typedef __attribute__((ext_vector_type(4))) short s16x4;
typedef __attribute__((ext_vector_type(2))) unsigned int u32x2;

__device__ __forceinline__ float bf2f(unsigned short u) {
  return __uint_as_float(((unsigned int)u) << 16);
}
__device__ __forceinline__ unsigned short f2bf(float f) {
  unsigned int u = __float_as_uint(f);
  u += 0x7fff + ((u >> 16) & 1);
  return (unsigned short)(u >> 16);
}

__device__ __forceinline__ float vexp2(float x) {
#if __has_builtin(__builtin_amdgcn_exp2f)
  return __builtin_amdgcn_exp2f(x);
#else
  return exp2f(x);
#endif
}

// pack hi16(e1):hi16(e0) into one dword (bf16 truncation)
__device__ __forceinline__ unsigned int pk_bf16_trunc(float e0, float e1) {
#if __has_builtin(__builtin_amdgcn_perm)
  return __builtin_amdgcn_perm(__float_as_uint(e1), __float_as_uint(e0), 0x07060302u);
#else
  return (__float_as_uint(e1) & 0xffff0000u) | (__float_as_uint(e0) >> 16);
#endif
}

// CDNA4 lane-row swaps (both outputs used).
__device__ __forceinline__ void pl32swap(unsigned int& a, unsigned int& b) {
#if __has_builtin(__builtin_amdgcn_permlane32_swap)
  u32x2 r = __builtin_amdgcn_permlane32_swap(a, b, false, false);
  a = r.x; b = r.y;
#else
  asm("v_permlane32_swap_b32 %0, %1" : "+v"(a), "+v"(b));
#endif
}
__device__ __forceinline__ void pl16swap(unsigned int& a, unsigned int& b) {
#if __has_builtin(__builtin_amdgcn_permlane16_swap)
  u32x2 r = __builtin_amdgcn_permlane16_swap(a, b, false, false);
  a = r.x; b = r.y;
#else
  asm("v_permlane16_swap_b32 %0, %1" : "+v"(a), "+v"(b));
#endif
}

__device__ __forceinline__ void gld_lds16(const unsigned short* g, unsigned short* l) {
  __builtin_amdgcn_global_load_lds((const __attribute__((address_space(1))) void*)g,
                                   (__attribute__((address_space(3))) void*)l,
                                   16, 0, 0);
}

// ---------------- sizes for the split casts ----------------------------------
#define N4_X   (BS * EMB / 4)
#define N4_QA  (QRANK * EMB / 4)
#define N4_KVA ((KVRANK + ROPED) * EMB / 4)
#define N4_QB  (NH * QKD * QRANK / 4)
#define N4_KVB (NH * 192 * KVRANK / 4)
#define N4_O   (EMB * NH * VD / 4)
#define N4A_TOT (N4_X + N4_QA + N4_KVA)
#define N4B_TOT (N4_QB + N4_KVB + N4_O)

// ---------------- cast A: x, q_a_w, kv_a_w (needed by G1) --------------------
__global__ void cast_a(const float* __restrict__ x, const float* __restrict__ qa,
                       const float* __restrict__ kva,
                       unsigned short* __restrict__ Xb, unsigned short* __restrict__ Wcomb) {
  int i = blockIdx.x * blockDim.x + threadIdx.x;
  int stride = gridDim.x * blockDim.x;
  for (; i < N4A_TOT; i += stride) {
    const float4* src;
    ushort4* dst;
    int j = i;
    if (j < N4_X) { src = (const float4*)x; dst = (ushort4*)Xb; }
    else if ((j -= N4_X) < N4_QA) { src = (const float4*)qa; dst = (ushort4*)Wcomb; }
    else { j -= N4_QA; src = (const float4*)kva; dst = (ushort4*)(Wcomb + (size_t)QRANK * EMB); }
    float4 v = src[j];
    ushort4 o;
    o.x = f2bf(v.x); o.y = f2bf(v.y); o.z = f2bf(v.z); o.w = f2bf(v.w);
    dst[j] = o;
  }
}

// ---------------- shared GEMM core: acc = A[128 rows] x W[128 rows]^T --------
// 128x128 tile, BK=64, 4 waves 2x2, 32KB LDS, __syncthreads schedule (v1 —
// measured best; dbuf regressed via occupancy loss, r6).
__device__ __forceinline__ void gemm_core(
    unsigned short* As, unsigned short* Ws,
    const unsigned short* __restrict__ A, int lda,
    const unsigned short* __restrict__ W, int ldw,
    int N, int K, int bm, int bn, bool clamp, f32x4 (&acc)[4][4]) {
  const int tid = threadIdx.x;
  const int wave = tid >> 6;
  const int lane = tid & 63;
  const int ln = lane & 15;
  const int quad = lane >> 4;
  const int wm = (wave >> 1) * 64;
  const int wn = (wave & 1) * 64;
  const int rel8 = lane >> 3;
  const int csw = ((lane & 7) ^ rel8) * 8;

  for (int k0 = 0; k0 < K; k0 += 64) {
#pragma unroll
    for (int it = 0; it < 4; ++it) {
      int rb = wave * 32 + it * 8;
      gld_lds16(A + (size_t)(bm + rb + rel8) * lda + k0 + csw, &As[rb * 64]);
    }
#pragma unroll
    for (int it = 0; it < 4; ++it) {
      int rb = wave * 32 + it * 8;
      int wr = bn + rb + rel8;
      if (clamp && wr >= N) wr = N - 1;
      gld_lds16(W + (size_t)wr * ldw + k0 + csw, &Ws[rb * 64]);
    }
    __syncthreads();
#pragma unroll
    for (int kk = 0; kk < 64; kk += 32) {
      s16x8 a[4], b[4];
#pragma unroll
      for (int mt = 0; mt < 4; ++mt)
        a[mt] = *(const s16x8*)&As[(wm + mt * 16 + ln) * 64 + ((kk / 8 + quad) ^ (ln & 7)) * 8];
#pragma unroll
      for (int nt = 0; nt < 4; ++nt)
        b[nt] = *(const s16x8*)&Ws[(wn + nt * 16 + ln) * 64 + ((kk / 8 + quad) ^ (ln & 7)) * 8];
#pragma unroll
      for (int mt = 0; mt < 4; ++mt)
#pragma unroll
        for (int nt = 0; nt < 4; ++nt)
          acc[mt][nt] = __builtin_amdgcn_mfma_f32_16x16x32_bf16(a[mt], b[nt], acc[mt][nt], 0, 0, 0);
    }
    __syncthreads();
  }
}

__device__ __forceinline__ void gemm_store(f32x4 (&acc)[4][4], void* C, int N,
                                           int bm, int bn, int out_f32) {
  const int tid = threadIdx.x;
  const int wave = tid >> 6;
  const int lane = tid & 63;
  const int ln = lane & 15;
  const int quad = lane >> 4;
  const int wm = (wave >> 1) * 64;
  const int wn = (wave & 1) * 64;
#pragma unroll
  for (int mt = 0; mt < 4; ++mt) {
    int row = bm + wm + mt * 16 + quad * 4;
#pragma unroll
    for (int nt = 0; nt < 4; ++nt) {
      int col = bn + wn + nt * 16 + ln;
      if (col < N) {
#pragma unroll
        for (int r = 0; r < 4; ++r) {
          float v = acc[mt][nt][r];
          if (out_f32)
            ((float*)C)[(size_t)(row + r) * N + col] = v;
          else
            ((unsigned short*)C)[(size_t)(row + r) * N + col] = f2bf(v);
        }
      }
    }
  }
}

// ---------------- G1 + fold-in cast of qb/kvb/ow -----------------------------
// Blocks 0..543: CQKV = Xb @ Wcomb^T (17x32 tiles, XCD-bijective swizzle).
// Blocks 544..2047: grid-stride cast of qb/kvb/ow (outputs first read by the
// NEXT launch, so overlapping them with G1 compute is safe). G1 occupies 544
// of 768 resident slots; cast blocks fill the idle slots + drain tail.
#define G1_BLOCKS 544
#define G1CAST_GRID 2048
__global__ __launch_bounds__(256, 3) void gemm_a_castb(
    const unsigned short* __restrict__ Xb, const unsigned short* __restrict__ Wcomb,
    unsigned short* __restrict__ CQKV,
    const float* __restrict__ qb, const float* __restrict__ kvb, const float* __restrict__ ow,
    unsigned short* __restrict__ Wqb, unsigned short* __restrict__ Wkvb,
    unsigned short* __restrict__ Wo) {
  __shared__ __align__(16) unsigned short As[128 * 64];
  __shared__ __align__(16) unsigned short Ws[128 * 64];
  const int bid = blockIdx.x;
  if (bid < G1_BLOCKS) {
    const int swz = (bid & 7) * (G1_BLOCKS / 8) + (bid >> 3);
    const int bm = (swz / 17) * 128;
    const int bn = (swz % 17) * 128;
    f32x4 acc[4][4] = {};
    gemm_core(As, Ws, Xb, EMB, Wcomb, EMB, NCOMB, EMB, bm, bn, true, acc);
    gemm_store(acc, CQKV, NCOMB, bm, bn, 0);
    return;
  }
  int i = (bid - G1_BLOCKS) * 256 + threadIdx.x;
  const int stride = (G1CAST_GRID - G1_BLOCKS) * 256;
  for (; i < N4B_TOT; i += stride) {
    const float4* src;
    ushort4* dst;
    int j = i;
    if (j < N4_QB) { src = (const float4*)qb; dst = (ushort4*)Wqb; }
    else if ((j -= N4_QB) < N4_KVB) { src = (const float4*)kvb; dst = (ushort4*)Wkvb; }
    else { j -= N4_KVB; src = (const float4*)ow; dst = (ushort4*)Wo; }
    float4 v = src[j];
    ushort4 o;
    o.x = f2bf(v.x); o.y = f2bf(v.y); o.z = f2bf(v.z); o.w = f2bf(v.w);
    dst[j] = o;
  }
}

// ---------------- merged Gq (RoPE epilogue) + Gkv, one launch ----------------
// Blocks 0..511: Qry = RoPE(CQKV[:, :1536] @ Wqb^T) — the long pole (K=1536),
// started first. Blocks 512..1279: KVB = CQKV[:, 1536:2048] @ Wkvb^T (K=512)
// fills Gq's tail. Both read only CQKV; independent outputs.
#define GQ_BLOCKS 512
#define GKV_BLOCKS 768
__global__ __launch_bounds__(256, 3) void gemm_qkv(
    const unsigned short* __restrict__ CQKV,
    const unsigned short* __restrict__ Wqb, const unsigned short* __restrict__ Wkvb,
    unsigned short* __restrict__ Qry, unsigned short* __restrict__ KVB) {
  __shared__ __align__(16) unsigned short As[128 * 64];
  __shared__ __align__(16) unsigned short Ws[128 * 64];
  const int bid = blockIdx.x;
  if (bid >= GQ_BLOCKS) {
    const int b2 = bid - GQ_BLOCKS;
    const int swz = (b2 & 7) * (GKV_BLOCKS / 8) + (b2 >> 3);
    const int bm = (swz / 24) * 128;
    const int bn = (swz % 24) * 128;
    f32x4 acc[4][4] = {};
    gemm_core(As, Ws, CQKV + QRANK, NCOMB, Wkvb, KVRANK, NH * 192, KVRANK, bm, bn, false, acc);
    gemm_store(acc, KVB, NH * 192, bm, bn, 0);
    return;
  }
  // ---- q path: fused RoPE + log2e + (B,H,S,128) permuted store
  const int swz = (bid & 7) * (GQ_BLOCKS / 8) + (bid >> 3);
  const int bm = (swz / 16) * 128;
  const int bn = (swz % 16) * 128;
  f32x4 acc[4][4] = {};
  gemm_core(As, Ws, CQKV, NCOMB, Wqb, QRANK, NH * QKD, QRANK, bm, bn, false, acc);

  const int tid = threadIdx.x;
  const int wave = tid >> 6;
  const int lane = tid & 63;
  const int ln = lane & 15;
  const int quad = lane >> 4;
  const int wm = (wave >> 1) * 64;
  const int wn = (wave & 1) * 64;
  const bool odd = (ln & 1);
#pragma unroll
  for (int mt = 0; mt < 4; ++mt) {
    int rowb = bm + wm + mt * 16 + quad * 4;
#pragma unroll
    for (int nt = 0; nt < 4; ++nt) {
      int col = bn + wn + nt * 16 + ln;
      int h = col >> 7, d = col & 127;
#pragma unroll
      for (int r = 0; r < 4; ++r) {
        float v = acc[mt][nt][r];
        float other = __shfl_xor(v, 1);
        int row = rowb + r;
        int b = row >> 11, s = row & 2047;
        float y = v;
        if (d >= NOPED) {
          int i = (d - NOPED) >> 1;
          float theta = exp2f(-(float)i * (13.287712379549449f / 32.f));
          float ang = (float)s * theta;
          float sn, c;
          sincosf(ang, &sn, &c);
          y = v * c + (odd ? other * sn : -other * sn);
        }
        y *= LOG2E;   // fold softmax exp->exp2 conversion into Q
        Qry[((size_t)(b * NH + h) * SEQ + s) * QKD + d] = f2bf(y);
      }
    }
  }
}

// ---------------- fused prep: Key (nope + RoPE) AND V^T, one KVB pass --------
// r8: Key-nope path vectorized (was 4096 scalar u16 loads/block; now 16B
// chunks from kvb / kr-LDS, 16B coalesced stores).
__global__ void prep_kv(const unsigned short* __restrict__ kvb,
                        const unsigned short* __restrict__ cqkv,
                        unsigned short* __restrict__ Key,
                        unsigned short* __restrict__ VT) {
  __shared__ unsigned short vt[64][132];
  __shared__ unsigned short kr[64][64];
  int blk = blockIdx.x;
  int bh = blk >> 5, st = blk & 31;
  int b = bh >> 4, h = bh & 15;
  int s0 = st * 64;
  int tid = threadIdx.x;

  // krot: 64 rows x 32 pairs
  for (int idx = tid; idx < 64 * 32; idx += 256) {
    int sl = idx >> 5, i = idx & 31;
    int s = s0 + sl;
    const unsigned short* rp = cqkv + (size_t)(b * SEQ + s) * NCOMB + QRANK + KVRANK;
    float x0 = bf2f(rp[2 * i]);
    float x1 = bf2f(rp[2 * i + 1]);
    float theta = exp2f(-(float)i * (13.287712379549449f / 32.f));
    float ang = (float)s * theta;
    float sn, c;
    sincosf(ang, &sn, &c);
    kr[sl][2 * i] = f2bf(x0 * c - x1 * sn);
    kr[sl][2 * i + 1] = f2bf(x1 * c + x0 * sn);
  }
  // V tile load (16B vectors)
  for (int idx = tid; idx < 64 * 16; idx += 256) {
    int sl = idx >> 4, dc = idx & 15;
    s16x8 v = *(const s16x8*)(kvb + (size_t)(b * SEQ + s0 + sl) * (NH * 192) + h * 192 + NOPED + dc * 8);
    *(s16x8*)&vt[sl][dc * 8] = v;
  }
  __syncthreads();
  // Key write in 16B chunks: dc<8 nope straight from kvb, dc>=8 from kr (LDS)
  for (int idx = tid; idx < 64 * 16; idx += 256) {
    int sl = idx >> 4, dc = idx & 15;
    s16x8 v;
    if (dc < 8)
      v = *(const s16x8*)(kvb + (size_t)(b * SEQ + s0 + sl) * (NH * 192) + h * 192 + dc * 8);
    else
      v = *(const s16x8*)&kr[sl][(dc - 8) * 8];
    *(s16x8*)&Key[((size_t)bh * SEQ + s0 + sl) * QKD + dc * 8] = v;
  }
  // V^T write
  for (int idx = tid; idx < 64 * 128; idx += 256) {
    int d = idx >> 6, sl = idx & 63;
    VT[((size_t)bh * VD + d) * SEQ + s0 + sl] = vt[sl][d];
  }
}

// ---------------- flash attention v10 (final): cross-tile pipeline -----------
// Probe history: v9 conflict-fix 93.6->88; v10 pipeline 86.6/77 (band);
// v11 48KB 114.7 (grid=2/CU); v12 QBLK=256 84.8 (1 blk/CU). v10 = best.
// LDS-read volume (full K+V tile per wave) is a structural invariant; more
// q-rows/wave exceeds the VGPR budget. Flash closed at ~76us.
__global__ __launch_bounds__(256, 2) void flash_attn(
    const unsigned short* __restrict__ Q,
    const unsigned short* __restrict__ Kt,     // (BHD, SEQ, 128)
    const unsigned short* __restrict__ VT,     // (BHD, 128, SEQ)
    unsigned short* __restrict__ O)
{
  __shared__ __align__(16) unsigned short Ks[2][64 * 128];
  __shared__ __align__(16) unsigned short Vs[3][128 * 64];

  const int tid = threadIdx.x;
  const int wave = tid >> 6;
  const int lane = tid & 63;
  const int ln = lane & 15;
  const int quad = lane >> 4;
  const int bh = blockIdx.x;
  const int q0 = blockIdx.y * 128;
  const int b = bh >> 4, h = bh & 15;

  // ---- Q fragments straight from global (B-operand of S^T = K·Q^T)
  s16x8 qa[2][4];
#pragma unroll
  for (int mt = 0; mt < 2; ++mt) {
    const unsigned short* qrow = Q + ((size_t)bh * SEQ + q0 + wave * 32 + mt * 16 + ln) * QKD;
#pragma unroll
    for (int kx = 0; kx < 4; ++kx)
      qa[mt][kx] = *(const s16x8*)(qrow + kx * 32 + quad * 8);
  }

  const int krel = lane >> 4, kcch = lane & 15;
  const int vrel8 = lane >> 3;
  const int vc8 = (lane & 7) ^ vrel8;

  // 8 async loads per wave per tile (4 K + 4 V); tile t -> Ks[t&1], Vs[t%3]
  auto stage = [&](unsigned short* Kd, unsigned short* Vd, int kt) {
#pragma unroll
    for (int it = 0; it < 4; ++it) {
      int rb = wave * 16 + it * 4;
      int rr = rb + krel;
      int c = kcch ^ (rr & 15);
      gld_lds16(Kt + ((size_t)bh * SEQ + kt * 64 + rr) * QKD + c * 8, Kd + rb * 128);
    }
#pragma unroll
    for (int it = 0; it < 4; ++it) {
      int rb = wave * 32 + it * 8;
      gld_lds16(VT + ((size_t)bh * VD + rb + vrel8) * SEQ + kt * 64 + vc8 * 8, Vd + rb * 64);
    }
  };

  f32x4 o[2][8] = {};              // o[mt][dt]: d = dt*16+quad*4+r, q = mt*16+ln
  float l_i[2] = {0.f, 0.f};

  // ---- chunk helpers (all inlined; call sites use literal args)
  auto sc_init = [&](f32x4 (&sc)[2][4]) {
#pragma unroll
    for (int mt = 0; mt < 2; ++mt)
#pragma unroll
      for (int t = 0; t < 4; ++t)
        sc[mt][t] = (f32x4){-20.f, -20.f, -20.f, -20.f};
  };
  auto qk_kx = [&](int kx, const unsigned short* Kc, f32x4 (&sc)[2][4]) {
    s16x8 ak[4];
#pragma unroll
    for (int t = 0; t < 4; ++t)
      ak[t] = *(const s16x8*)&Kc[(t * 16 + ln) * 128 + ((kx * 4 + quad) ^ ln) * 8];
#pragma unroll
    for (int mt = 0; mt < 2; ++mt)
#pragma unroll
      for (int t = 0; t < 4; ++t)
        sc[mt][t] = __builtin_amdgcn_mfma_f32_16x16x32_bf16(ak[t], qa[mt][kx], sc[mt][t], 0, 0, 0);
  };
  auto sm_mt = [&](int mt, f32x4 (&sc)[2][4], s16x8 (&pfrag)[2][2]) {
    float rs = 0.f;
    unsigned int pw[4][2];
#pragma unroll
    for (int t = 0; t < 4; ++t) {
      float e0 = vexp2(sc[mt][t][0]);
      float e1 = vexp2(sc[mt][t][1]);
      float e2 = vexp2(sc[mt][t][2]);
      float e3 = vexp2(sc[mt][t][3]);
      unsigned int p01 = pk_bf16_trunc(e0, e1);
      unsigned int p23 = pk_bf16_trunc(e2, e3);
      pw[t][0] = p01; pw[t][1] = p23;
      rs += (__uint_as_float(p01 << 16) + __uint_as_float(p01 & 0xffff0000u))
          + (__uint_as_float(p23 << 16) + __uint_as_float(p23 & 0xffff0000u));
    }
    rs += __shfl_xor(rs, 16);
    rs += __shfl_xor(rs, 32);
    l_i[mt] += rs;
#pragma unroll
    for (int W = 0; W < 2; ++W) {
      unsigned int u0 = pw[2 * W][0], v0 = pw[2 * W + 1][0];
      unsigned int u1 = pw[2 * W][1], v1 = pw[2 * W + 1][1];
      pl32swap(u0, v0); pl16swap(u0, v0);
      pl32swap(u1, v1); pl16swap(u1, v1);
      union { unsigned int u[4]; s16x8 v; } fb;
      fb.u[0] = u0;    // k_local = quad*8 + {0,1}
      fb.u[1] = u1;    // k_local = quad*8 + {2,3}
      fb.u[2] = v0;    // k_local = quad*8 + {4,5}
      fb.u[3] = v1;    // k_local = quad*8 + {6,7}
      pfrag[mt][W] = fb.v;
    }
  };
  auto pv_half = [&](int half, const unsigned short* Vc, s16x8 (&pfrag)[2][2]) {
#pragma unroll
    for (int dd = 0; dd < 4; ++dd) {
      int dt = half * 4 + dd;
      s16x8 av0 = *(const s16x8*)&Vc[(dt * 16 + ln) * 64 + ((quad ^ (ln & 7)) * 8)];
      s16x8 av1 = *(const s16x8*)&Vc[(dt * 16 + ln) * 64 + (((4 + quad) ^ (ln & 7)) * 8)];
#pragma unroll
      for (int mt = 0; mt < 2; ++mt) {
        o[mt][dt] = __builtin_amdgcn_mfma_f32_16x16x32_bf16(av0, pfrag[mt][0], o[mt][dt], 0, 0, 0);
        o[mt][dt] = __builtin_amdgcn_mfma_f32_16x16x32_bf16(av1, pfrag[mt][1], o[mt][dt], 0, 0, 0);
      }
    }
  };

  // ---- pipelined iteration: QK(kt)->scC interleaved with softmax+PV(kt-1)
  auto iter = [&](int kt, f32x4 (&scP)[2][4], f32x4 (&scC)[2][4]) {
    asm volatile("s_waitcnt vmcnt(0)" ::: "memory");     // tile kt staged
    asm volatile("s_barrier" ::: "memory");              // all reads of (kt+1)-buffers done
    if (kt + 1 < NT)
      stage(Ks[(kt + 1) & 1], Vs[(kt + 1) % 3], kt + 1);
    const unsigned short* Kc = Ks[kt & 1];
    const unsigned short* Vp = Vs[(kt - 1) % 3];
    s16x8 pfrag[2][2];
    __builtin_amdgcn_s_setprio(1);
    sc_init(scC);
    qk_kx(0, Kc, scC);
    sm_mt(0, scP, pfrag);
    qk_kx(1, Kc, scC);
    sm_mt(1, scP, pfrag);
    qk_kx(2, Kc, scC);
    pv_half(0, Vp, pfrag);
    qk_kx(3, Kc, scC);
    pv_half(1, Vp, pfrag);
    __builtin_amdgcn_s_setprio(0);
  };

  f32x4 scA[2][4], scB[2][4];

  // prologue: stage tiles 0 and 1; QK(0) -> scA
  stage(Ks[0], Vs[0], 0);
  asm volatile("s_waitcnt vmcnt(0)" ::: "memory");
  asm volatile("s_barrier" ::: "memory");
  stage(Ks[1], Vs[1], 1);
  __builtin_amdgcn_s_setprio(1);
  sc_init(scA);
  qk_kx(0, Ks[0], scA);
  qk_kx(1, Ks[0], scA);
  qk_kx(2, Ks[0], scA);
  qk_kx(3, Ks[0], scA);
  __builtin_amdgcn_s_setprio(0);

  // 15 pairs cover kt = 1..30 with static sc ping-pong
  int kt = 1;
#pragma unroll 1
  for (int p = 0; p < 15; ++p, kt += 2) {
    iter(kt, scA, scB);
    iter(kt + 1, scB, scA);
  }
  iter(31, scA, scB);

  // epilogue: softmax+PV for tile 31 (V in Vs[31 % 3] = Vs[1])
  {
    s16x8 pfrag[2][2];
    sm_mt(0, scB, pfrag);
    sm_mt(1, scB, pfrag);
    pv_half(0, Vs[1], pfrag);
    pv_half(1, Vs[1], pfrag);
  }

#pragma unroll
  for (int mt = 0; mt < 2; ++mt) {
    float inv = 1.f / l_i[mt];
    int s = q0 + wave * 32 + mt * 16 + ln;
    size_t rowbase = ((size_t)b * SEQ + s) * (NH * VD) + h * VD;
#pragma unroll
    for (int dt = 0; dt < 8; ++dt) {
      ushort4 pk;
      pk.x = f2bf(o[mt][dt][0] * inv);
      pk.y = f2bf(o[mt][dt][1] * inv);
      pk.z = f2bf(o[mt][dt][2] * inv);
      pk.w = f2bf(o[mt][dt][3] * inv);
      *(ushort4*)&O[rowbase + dt * 16 + quad * 4] = pk;
    }
  }
}

// ---------------- Go: out = AO @ o_w^T (fp32 out), swizzled flat grid --------
__global__ __launch_bounds__(256, 3) void gemm_out(
    const unsigned short* __restrict__ A, int lda,
    const unsigned short* __restrict__ W, int ldw,
    float* __restrict__ C, int N, int K) {
  __shared__ __align__(16) unsigned short As[128 * 64];
  __shared__ __align__(16) unsigned short Ws[128 * 64];
  const int nwg = gridDim.x;
  const int cpx = nwg >> 3;
  const int swz = (blockIdx.x & 7) * cpx + (blockIdx.x >> 3);
  const int nbx = N >> 7;
  const int bm = (swz / nbx) * 128;
  const int bn = (swz % nbx) * 128;
  f32x4 acc[4][4] = {};
  gemm_core(As, Ws, A, lda, W, ldw, N, K, bm, bn, false, acc);
  gemm_store(acc, C, N, bm, bn, 1);
}

extern "C" void kernel_launch(void* const* d_in, const int* in_sizes, int n_in,
                              void* d_out, int out_size, void* d_ws, size_t ws_size,
                              hipStream_t stream) {
  const float* x_f    = (const float*)d_in[0];
  const float* qaw_f  = (const float*)d_in[1];
  const float* qbw_f  = (const float*)d_in[2];
  const float* kvaw_f = (const float*)d_in[3];
  const float* kvbw_f = (const float*)d_in[4];
  const float* ow_f   = (const float*)d_in[5];

  char* ws = (char*)d_ws;
  size_t off = 0;
  auto alloc = [&](size_t n) {
    unsigned short* p = (unsigned short*)(ws + off);
    off = (off + n * 2 + 255) & ~(size_t)255;
    return p;
  };
  unsigned short* Xb    = alloc((size_t)BS * EMB);
  unsigned short* Wcomb = alloc((size_t)NCOMB * EMB);
  unsigned short* Wqb   = alloc((size_t)(NH * QKD) * QRANK);
  unsigned short* Wkvb  = alloc((size_t)(NH * 192) * KVRANK);
  unsigned short* Wo    = alloc((size_t)EMB * (NH * VD));
  unsigned short* CQKV  = alloc((size_t)BS * NCOMB);
  unsigned short* KVB   = alloc((size_t)BS * (NH * 192));
  unsigned short* Qry   = alloc((size_t)BHD * SEQ * QKD);
  unsigned short* Key   = alloc((size_t)BHD * SEQ * QKD);
  unsigned short* Vt    = alloc((size_t)BHD * VD * SEQ);
  unsigned short* AO    = alloc((size_t)BS * (NH * VD));

  // cast only what G1 needs (x, q_a_w, kv_a_w)
  cast_a<<<dim3(4096), 256, 0, stream>>>(x_f, qaw_f, kvaw_f, Xb, Wcomb);

  // G1 (544 blocks) + folded cast of qb/kvb/ow (1504 blocks)
  gemm_a_castb<<<dim3(G1CAST_GRID), 256, 0, stream>>>(
      Xb, Wcomb, CQKV, qbw_f, kvbw_f, ow_f, Wqb, Wkvb, Wo);

  // merged Gq (RoPE, blocks 0..511) + Gkv (blocks 512..1279)
  gemm_qkv<<<dim3(GQ_BLOCKS + GKV_BLOCKS), 256, 0, stream>>>(
      CQKV, Wqb, Wkvb, Qry, KVB);

  // fused Key + V^T prep (one KVB pass, one launch)
  prep_kv<<<dim3(BHD * (SEQ / 64)), 256, 0, stream>>>(KVB, CQKV, Key, Vt);

  flash_attn<<<dim3(BHD, SEQ / 128), 256, 0, stream>>>(Qry, Key, Vt, AO);

  // out = AO @ o_w^T (fp32 out); grid 16*32 = 512
  gemm_out<<<dim3((EMB / 128) * (BS / 128)), 256, 0, stream>>>(
      AO, NH * VD, Wo, NH * VD, (float*)d_out, EMB, NH * VD);
}